// Round 2
// baseline (889.945 us; speedup 1.0000x reference)
//
#include <hip/hip_runtime.h>
#include <limits.h>
#include <math.h>

// ---------------------------------------------------------------------------
// (val, idx) comparator with stable lowest-index tie-break, matching
// jax.lax.top_k semantics (smallest-k via reference's negate also gives
// lowest-index-wins on original-value ties).
// ---------------------------------------------------------------------------
template<bool LG>
__device__ __forceinline__ bool better(float v, int i, float w, int j) {
    return LG ? (v > w || (v == w && i < j))
              : (v < w || (v == w && i < j));
}

// Insert into best-first sorted 4-list. Static indexing only.
template<bool LG>
__device__ __forceinline__ void ins4(float x, int xi,
    float& s0, float& s1, float& s2, float& s3,
    int& j0, int& j1, int& j2, int& j3)
{
    if (!better<LG>(x, xi, s3, j3)) return;
    if (better<LG>(x, xi, s2, j2)) {
        s3 = s2; j3 = j2;
        if (better<LG>(x, xi, s1, j1)) {
            s2 = s1; j2 = j1;
            if (better<LG>(x, xi, s0, j0)) { s1 = s0; j1 = j0; s0 = x; j0 = xi; }
            else                           { s1 = x;  j1 = xi; }
        } else { s2 = x; j2 = xi; }
    } else { s3 = x; j3 = xi; }
}

// Insert into best-first sorted 3-list.
template<bool LG>
__device__ __forceinline__ void ins3(float x, int xi,
    float& s0, float& s1, float& s2,
    int& j0, int& j1, int& j2)
{
    if (!better<LG>(x, xi, s2, j2)) return;
    if (better<LG>(x, xi, s1, j1)) {
        s2 = s1; j2 = j1;
        if (better<LG>(x, xi, s0, j0)) { s1 = s0; j1 = j0; s0 = x; j0 = xi; }
        else                           { s1 = x;  j1 = xi; }
    } else { s2 = x; j2 = xi; }
}

// Compare-exchange: ensure x is the better element.
template<bool LG>
__device__ __forceinline__ void ce(float& x, int& xi, float& y, int& yi) {
    if (!better<LG>(x, xi, y, yi)) {
        float tv = x; x = y; y = tv;
        int   ti = xi; xi = yi; yi = ti;
    }
}

// Merge two best-first sorted 4-lists -> best 4 (into A). Bitonic.
template<bool LG>
__device__ __forceinline__ void merge4(
    float& a0, float& a1, float& a2, float& a3,
    int& i0, int& i1, int& i2, int& i3,
    float b0, float b1, float b2, float b3,
    int j0, int j1, int j2, int j3)
{
    bool c;
    float l0, l1, l2, l3; int m0, m1, m2, m3;
    c = better<LG>(a0, i0, b3, j3); l0 = c ? a0 : b3; m0 = c ? i0 : j3;
    c = better<LG>(a1, i1, b2, j2); l1 = c ? a1 : b2; m1 = c ? i1 : j2;
    c = better<LG>(a2, i2, b1, j1); l2 = c ? a2 : b1; m2 = c ? i2 : j1;
    c = better<LG>(a3, i3, b0, j0); l3 = c ? a3 : b0; m3 = c ? i3 : j0;
    ce<LG>(l0, m0, l2, m2); ce<LG>(l1, m1, l3, m3);
    ce<LG>(l0, m0, l1, m1); ce<LG>(l2, m2, l3, m3);
    a0 = l0; a1 = l1; a2 = l2; a3 = l3;
    i0 = m0; i1 = m1; i2 = m2; i3 = m3;
}

// ---------------------------------------------------------------------------
// Kernel 0: v_0 (4096, 32000), top-2 largest along dim 1. One wave per row.
// Loads batched 4x (64 B/thread in flight) BEFORE the branchy update code.
// ---------------------------------------------------------------------------
__device__ __forceinline__ void upd2(float xv, int xi,
    float& a0, float& a1, int& i0, int& i1)
{
    if (better<true>(xv, xi, a1, i1)) {
        if (better<true>(xv, xi, a0, i0)) { a1 = a0; i1 = i0; a0 = xv; i0 = xi; }
        else                              { a1 = xv; i1 = xi; }
    }
}

__device__ __forceinline__ void upd2v(float4 t, int base,
    float& a0, float& a1, int& i0, int& i1)
{
    upd2(t.x, base,     a0, a1, i0, i1);
    upd2(t.y, base + 1, a0, a1, i0, i1);
    upd2(t.z, base + 2, a0, a1, i0, i1);
    upd2(t.w, base + 3, a0, a1, i0, i1);
}

__global__ __launch_bounds__(256) void topk0_kernel(
    const float* __restrict__ x, float* __restrict__ outv, float* __restrict__ outi)
{
    const int wave = threadIdx.x >> 6;
    const int lane = threadIdx.x & 63;
    const int row  = blockIdx.x * 4 + wave;
    const float4* xr = (const float4*)(x + (size_t)row * 32000);

    float a0 = -INFINITY, a1 = -INFINITY;
    int   i0 = INT_MAX,   i1 = INT_MAX;

    // 8000 float4 per row; 125 per lane = 31*4 + 1
    int v = lane;
    for (int it = 0; it < 31; ++it, v += 256) {
        float4 t0 = xr[v];
        float4 t1 = xr[v + 64];
        float4 t2 = xr[v + 128];
        float4 t3 = xr[v + 192];
        upd2v(t0, v * 4,          a0, a1, i0, i1);
        upd2v(t1, (v + 64) * 4,   a0, a1, i0, i1);
        upd2v(t2, (v + 128) * 4,  a0, a1, i0, i1);
        upd2v(t3, (v + 192) * 4,  a0, a1, i0, i1);
    }
    {   // tail: v = lane + 7936 < 8000
        float4 t = xr[v];
        upd2v(t, v * 4, a0, a1, i0, i1);
    }

    // butterfly merge of sorted 2-lists across the wave
    for (int m = 1; m < 64; m <<= 1) {
        float b0 = __shfl_xor(a0, m); int j0 = __shfl_xor(i0, m);
        float b1 = __shfl_xor(a1, m); int j1 = __shfl_xor(i1, m);
        bool c = better<true>(a0, i0, b0, j0);
        float r0 = c ? a0 : b0; int q0 = c ? i0 : j0;
        float ws = c ? a1 : b1; int wi = c ? i1 : j1;
        float lh = c ? b0 : a0; int li = c ? j0 : i0;
        bool c2 = better<true>(ws, wi, lh, li);
        a0 = r0; i0 = q0;
        a1 = c2 ? ws : lh; i1 = c2 ? wi : li;
    }

    if (lane == 0) {
        outv[row * 2 + 0] = a0;        outv[row * 2 + 1] = a1;
        outi[row * 2 + 0] = (float)i0; outi[row * 2 + 1] = (float)i1;
    }
}

// ---------------------------------------------------------------------------
// Kernel 1: v_1 (8192 rows, 4096), top-4 smallest along last dim. Wave/row.
// ---------------------------------------------------------------------------
__global__ __launch_bounds__(256) void topk1_kernel(
    const float* __restrict__ x, float* __restrict__ outv, float* __restrict__ outi)
{
    const int wave = threadIdx.x >> 6;
    const int lane = threadIdx.x & 63;
    const int row  = blockIdx.x * 4 + wave;
    const float4* xr = (const float4*)(x + (size_t)row * 4096);

    float s0 = INFINITY, s1 = INFINITY, s2 = INFINITY, s3 = INFINITY;
    int   j0 = INT_MAX,  j1 = INT_MAX,  j2 = INT_MAX,  j3 = INT_MAX;

#define INS4F(t, b) \
    ins4<false>((t).x, (b),     s0, s1, s2, s3, j0, j1, j2, j3); \
    ins4<false>((t).y, (b) + 1, s0, s1, s2, s3, j0, j1, j2, j3); \
    ins4<false>((t).z, (b) + 2, s0, s1, s2, s3, j0, j1, j2, j3); \
    ins4<false>((t).w, (b) + 3, s0, s1, s2, s3, j0, j1, j2, j3)

    // 1024 float4 per row; 16 per lane = 4*4
    int v = lane;
    for (int it = 0; it < 4; ++it, v += 256) {
        float4 t0 = xr[v];
        float4 t1 = xr[v + 64];
        float4 t2 = xr[v + 128];
        float4 t3 = xr[v + 192];
        INS4F(t0, v * 4);
        INS4F(t1, (v + 64) * 4);
        INS4F(t2, (v + 128) * 4);
        INS4F(t3, (v + 192) * 4);
    }
#undef INS4F

    for (int m = 1; m < 64; m <<= 1) {
        float b0 = __shfl_xor(s0, m), b1 = __shfl_xor(s1, m);
        float b2 = __shfl_xor(s2, m), b3 = __shfl_xor(s3, m);
        int   q0 = __shfl_xor(j0, m), q1 = __shfl_xor(j1, m);
        int   q2 = __shfl_xor(j2, m), q3 = __shfl_xor(j3, m);
        merge4<false>(s0, s1, s2, s3, j0, j1, j2, j3, b0, b1, b2, b3, q0, q1, q2, q3);
    }

    if (lane == 0) {
        outv[row * 4 + 0] = s0; outv[row * 4 + 1] = s1;
        outv[row * 4 + 2] = s2; outv[row * 4 + 3] = s3;
        outi[row * 4 + 0] = (float)j0; outi[row * 4 + 1] = (float)j1;
        outi[row * 4 + 2] = (float)j2; outi[row * 4 + 3] = (float)j3;
    }
}

// ---------------------------------------------------------------------------
// Kernel 2 phase 1: v_2 (100000, 512), top-3 largest along dim 0.
// Each thread owns 4 columns (float4) and one row-parity within the block's
// row chunk. 4 independent float4 loads in flight per iteration. Partials
// written float4-coalesced in [p][3][512] layout (p = blk*2 + parity).
// ---------------------------------------------------------------------------
__global__ __launch_bounds__(256) void topk2_p1(
    const float* __restrict__ x, float* __restrict__ pval, int* __restrict__ pidx,
    int rpb)
{
    const int blk = blockIdx.x;
    const int t   = threadIdx.x;
    const int h   = t >> 7;          // row parity
    const int c0  = (t & 127) * 4;   // column group
    int rbeg = blk * rpb;
    int rend = rbeg + rpb; if (rend > 100000) rend = 100000;

    float A0 = -INFINITY, A1 = -INFINITY, A2 = -INFINITY;
    float B0 = -INFINITY, B1 = -INFINITY, B2 = -INFINITY;
    float C0 = -INFINITY, C1 = -INFINITY, C2 = -INFINITY;
    float D0 = -INFINITY, D1 = -INFINITY, D2 = -INFINITY;
    int Ai0 = INT_MAX, Ai1 = INT_MAX, Ai2 = INT_MAX;
    int Bi0 = INT_MAX, Bi1 = INT_MAX, Bi2 = INT_MAX;
    int Ci0 = INT_MAX, Ci1 = INT_MAX, Ci2 = INT_MAX;
    int Di0 = INT_MAX, Di1 = INT_MAX, Di2 = INT_MAX;

#define LOAD4(r) (*(const float4*)(x + (size_t)(r) * 512 + c0))
#define COLUPD(vec, r) \
    ins3<true>((vec).x, (r), A0, A1, A2, Ai0, Ai1, Ai2); \
    ins3<true>((vec).y, (r), B0, B1, B2, Bi0, Bi1, Bi2); \
    ins3<true>((vec).z, (r), C0, C1, C2, Ci0, Ci1, Ci2); \
    ins3<true>((vec).w, (r), D0, D1, D2, Di0, Di1, Di2)

    int r = rbeg + h;
    for (; r + 6 < rend; r += 8) {
        float4 t0 = LOAD4(r);
        float4 t1 = LOAD4(r + 2);
        float4 t2 = LOAD4(r + 4);
        float4 t3 = LOAD4(r + 6);
        COLUPD(t0, r); COLUPD(t1, r + 2); COLUPD(t2, r + 4); COLUPD(t3, r + 6);
    }
    for (; r < rend; r += 2) {
        float4 t0 = LOAD4(r);
        COLUPD(t0, r);
    }
#undef LOAD4
#undef COLUPD

    const int p = blk * 2 + h;
    float* pv = pval + (size_t)p * 3 * 512;
    *(float4*)(pv + 0 * 512 + c0) = make_float4(A0, B0, C0, D0);
    *(float4*)(pv + 1 * 512 + c0) = make_float4(A1, B1, C1, D1);
    *(float4*)(pv + 2 * 512 + c0) = make_float4(A2, B2, C2, D2);
    int* pi = pidx + (size_t)p * 3 * 512;
    *(int4*)(pi + 0 * 512 + c0) = make_int4(Ai0, Bi0, Ci0, Di0);
    *(int4*)(pi + 1 * 512 + c0) = make_int4(Ai1, Bi1, Ci1, Di1);
    *(int4*)(pi + 2 * 512 + c0) = make_int4(Ai2, Bi2, Ci2, Di2);
}

// Phase 2: merge np partial top-3 lists per column. One wave per column.
__global__ __launch_bounds__(256) void topk2_p2(
    const float* __restrict__ pval, const int* __restrict__ pidx,
    float* __restrict__ outv, float* __restrict__ outi, int np)
{
    const int wave = threadIdx.x >> 6;
    const int lane = threadIdx.x & 63;
    const int col  = blockIdx.x * 4 + wave;

    float s0 = -INFINITY, s1 = -INFINITY, s2 = -INFINITY, s3 = -INFINITY;
    int   j0 = INT_MAX,   j1 = INT_MAX,   j2 = INT_MAX,   j3 = INT_MAX;

    for (int p = lane; p < np; p += 64) {
        const float* pv = pval + (size_t)p * 3 * 512 + col;
        const int*   pi = pidx + (size_t)p * 3 * 512 + col;
        float v0 = pv[0], v1 = pv[512], v2 = pv[1024];
        int   w0 = pi[0], w1 = pi[512], w2 = pi[1024];
        ins4<true>(v0, w0, s0, s1, s2, s3, j0, j1, j2, j3);
        ins4<true>(v1, w1, s0, s1, s2, s3, j0, j1, j2, j3);
        ins4<true>(v2, w2, s0, s1, s2, s3, j0, j1, j2, j3);
    }

    for (int m = 1; m < 64; m <<= 1) {
        float b0 = __shfl_xor(s0, m), b1 = __shfl_xor(s1, m);
        float b2 = __shfl_xor(s2, m), b3 = __shfl_xor(s3, m);
        int   q0 = __shfl_xor(j0, m), q1 = __shfl_xor(j1, m);
        int   q2 = __shfl_xor(j2, m), q3 = __shfl_xor(j3, m);
        merge4<true>(s0, s1, s2, s3, j0, j1, j2, j3, b0, b1, b2, b3, q0, q1, q2, q3);
    }

    if (lane == 0) {
        outv[0 * 512 + col] = s0; outv[1 * 512 + col] = s1; outv[2 * 512 + col] = s2;
        outi[0 * 512 + col] = (float)j0; outi[1 * 512 + col] = (float)j1; outi[2 * 512 + col] = (float)j2;
    }
}

// Fallback if workspace is too small: one block per column, block reduce.
__global__ __launch_bounds__(256) void topk2_direct(
    const float* __restrict__ x, float* __restrict__ outv, float* __restrict__ outi)
{
    const int col  = blockIdx.x;
    const int wave = threadIdx.x >> 6;
    const int lane = threadIdx.x & 63;

    float s0 = -INFINITY, s1 = -INFINITY, s2 = -INFINITY, s3 = -INFINITY;
    int   j0 = INT_MAX,   j1 = INT_MAX,   j2 = INT_MAX,   j3 = INT_MAX;

    for (int r = threadIdx.x; r < 100000; r += 256) {
        float v = x[(size_t)r * 512 + col];
        ins4<true>(v, r, s0, s1, s2, s3, j0, j1, j2, j3);
    }
    for (int m = 1; m < 64; m <<= 1) {
        float b0 = __shfl_xor(s0, m), b1 = __shfl_xor(s1, m);
        float b2 = __shfl_xor(s2, m), b3 = __shfl_xor(s3, m);
        int   q0 = __shfl_xor(j0, m), q1 = __shfl_xor(j1, m);
        int   q2 = __shfl_xor(j2, m), q3 = __shfl_xor(j3, m);
        merge4<true>(s0, s1, s2, s3, j0, j1, j2, j3, b0, b1, b2, b3, q0, q1, q2, q3);
    }
    __shared__ float sv[4][4];
    __shared__ int   si[4][4];
    if (lane == 0) {
        sv[wave][0] = s0; sv[wave][1] = s1; sv[wave][2] = s2; sv[wave][3] = s3;
        si[wave][0] = j0; si[wave][1] = j1; si[wave][2] = j2; si[wave][3] = j3;
    }
    __syncthreads();
    if (threadIdx.x == 0) {
        float r0 = sv[0][0], r1 = sv[0][1], r2 = sv[0][2], r3 = sv[0][3];
        int   k0 = si[0][0], k1 = si[0][1], k2 = si[0][2], k3 = si[0][3];
        for (int w = 1; w < 4; ++w) {
            merge4<true>(r0, r1, r2, r3, k0, k1, k2, k3,
                         sv[w][0], sv[w][1], sv[w][2], sv[w][3],
                         si[w][0], si[w][1], si[w][2], si[w][3]);
        }
        outv[0 * 512 + col] = r0; outv[1 * 512 + col] = r1; outv[2 * 512 + col] = r2;
        outi[0 * 512 + col] = (float)k0; outi[1 * 512 + col] = (float)k1; outi[2 * 512 + col] = (float)k2;
    }
}

extern "C" void kernel_launch(void* const* d_in, const int* in_sizes, int n_in,
                              void* d_out, int out_size, void* d_ws, size_t ws_size,
                              hipStream_t stream) {
    const float* v0 = (const float*)d_in[0];   // (4096, 32000)
    const float* v1 = (const float*)d_in[1];   // (8, 16, 64, 4096)
    const float* v2 = (const float*)d_in[2];   // (100000, 512)
    float* out = (float*)d_out;

    float* o_v4  = out;                 // (4096, 2) values
    float* o_v5  = out + 8192;          // (4096, 2) indices
    float* o_v7  = out + 16384;         // (8,16,64,4) values
    float* o_v8  = out + 49152;         // (8,16,64,4) indices
    float* o_v10 = out + 81920;         // (3, 512) values
    float* o_v11 = out + 83456;         // (3, 512) indices

    topk0_kernel<<<1024, 256, 0, stream>>>(v0, o_v4, o_v5);
    topk1_kernel<<<2048, 256, 0, stream>>>(v1, o_v7, o_v8);

    // TopK_2: two-phase. Workspace per block: 2 partials * 3 * 512 * 8 B = 24576 B.
    size_t per_block_bytes = 2ull * 3ull * 512ull * 8ull;
    int nb = (int)(ws_size / per_block_bytes);
    if (nb > 1024) nb = 1024;
    if (nb >= 1) {
        int rpb = (100000 + nb - 1) / nb;
        int np  = nb * 2;
        float* pval = (float*)d_ws;
        int*   pidx = (int*)(pval + (size_t)np * 3 * 512);
        topk2_p1<<<nb, 256, 0, stream>>>(v2, pval, pidx, rpb);
        topk2_p2<<<128, 256, 0, stream>>>(pval, pidx, o_v10, o_v11, np);
    } else {
        topk2_direct<<<512, 256, 0, stream>>>(v2, o_v10, o_v11);
    }
}

// Round 3
// 199.768 us; speedup vs baseline: 4.4549x; 4.4549x over previous
//
#include <hip/hip_runtime.h>
#include <limits.h>
#include <math.h>

typedef unsigned long long u64;
typedef unsigned int u32;

// ---------------------------------------------------------------------------
// Sortable-key top-k: pack (f32 value, index) into one u64 so that plain
// unsigned max (largest-k) / min (smallest-k) implements jax.lax.top_k's
// ordering including the lowest-index-wins tie-break.
//   ord(v): monotonic f32 -> u32 (sign-flip trick), bit-exact invertible.
//   largest : key = ord(v)<<32 | ~idx   (max; tie -> larger ~idx -> smaller idx)
//   smallest: key = ord(v)<<32 |  idx   (min; tie -> smaller idx)
// Sentinels: 0 for largest (loses to any real key), ~0ull for smallest.
// ---------------------------------------------------------------------------
__device__ __forceinline__ u32 f2ord(float v) {
    u32 u = __float_as_uint(v);
    return (u & 0x80000000u) ? ~u : (u | 0x80000000u);
}
__device__ __forceinline__ float ord2f(u32 s) {
    u32 u = (s & 0x80000000u) ? (s & 0x7FFFFFFFu) : ~s;
    return __uint_as_float(u);
}
__device__ __forceinline__ u64 keylg(float v, u32 i) { return ((u64)f2ord(v) << 32) | (u64)(~i); }
__device__ __forceinline__ u64 keysm(float v, u32 i) { return ((u64)f2ord(v) << 32) | (u64)i; }
__device__ __forceinline__ float val_of(u64 k) { return ord2f((u32)(k >> 32)); }
__device__ __forceinline__ float idxf_lg(u64 k) { return (float)(~(u32)k); }
__device__ __forceinline__ float idxf_sm(u64 k) { return (float)((u32)k); }

__device__ __forceinline__ u64 mx64(u64 a, u64 b) { return a > b ? a : b; }
__device__ __forceinline__ u64 mn64(u64 a, u64 b) { return a < b ? a : b; }

// Branchless inserts into sorted lists (descending for largest, ascending for
// smallest). 2k-1 u64 min/max ops, no divergence.
__device__ __forceinline__ void ins2_lg(u64& s0, u64& s1, u64 k) {
    u64 t0 = mx64(s0, k), r0 = mn64(s0, k);
    s0 = t0; s1 = mx64(s1, r0);
}
__device__ __forceinline__ void ins3_lg(u64& s0, u64& s1, u64& s2, u64 k) {
    u64 t0 = mx64(s0, k), r0 = mn64(s0, k);
    u64 t1 = mx64(s1, r0), r1 = mn64(s1, r0);
    s0 = t0; s1 = t1; s2 = mx64(s2, r1);
}
__device__ __forceinline__ void ins4_sm(u64& s0, u64& s1, u64& s2, u64& s3, u64 k) {
    u64 t0 = mn64(s0, k), r0 = mx64(s0, k);
    u64 t1 = mn64(s1, r0), r1 = mx64(s1, r0);
    u64 t2 = mn64(s2, r1), r2 = mx64(s2, r1);
    s0 = t0; s1 = t1; s2 = t2; s3 = mn64(s3, r2);
}

__device__ __forceinline__ void ce_max(u64& a, u64& b) { u64 h = mx64(a, b), l = mn64(a, b); a = h; b = l; }
__device__ __forceinline__ void ce_min(u64& a, u64& b) { u64 l = mn64(a, b), h = mx64(a, b); a = l; b = h; }

// Merge two sorted lists -> best k (bitonic; branchless).
__device__ __forceinline__ void merge2_lg(u64& a0, u64& a1, u64 b0, u64 b1) {
    u64 l0 = mx64(a0, b1), l1 = mx64(a1, b0);
    a0 = mx64(l0, l1); a1 = mn64(l0, l1);
}
__device__ __forceinline__ void merge3_lg(u64& a0, u64& a1, u64& a2, u64 b0, u64 b1, u64 b2) {
    u64 l0 = mx64(a0, b2), l1 = mx64(a1, b1), l2 = mx64(a2, b0);
    ce_max(l0, l1); ce_max(l1, l2); ce_max(l0, l1);   // full 3-sort network
    a0 = l0; a1 = l1; a2 = l2;
}
__device__ __forceinline__ void merge4_sm(u64& a0, u64& a1, u64& a2, u64& a3,
                                          u64 b0, u64 b1, u64 b2, u64 b3) {
    u64 l0 = mn64(a0, b3), l1 = mn64(a1, b2), l2 = mn64(a2, b1), l3 = mn64(a3, b0);
    ce_min(l0, l2); ce_min(l1, l3); ce_min(l0, l1); ce_min(l2, l3);  // bitonic 4-sorter
    a0 = l0; a1 = l1; a2 = l2; a3 = l3;
}

__device__ __forceinline__ u64 shx64(u64 v, int m) {
    u32 hi = __shfl_xor((u32)(v >> 32), m);
    u32 lo = __shfl_xor((u32)v, m);
    return ((u64)hi << 32) | (u64)lo;
}

// ---------------------------------------------------------------------------
// Kernel 0: v_0 (4096, 32000), top-2 largest along dim 1. One wave per row.
// ---------------------------------------------------------------------------
__global__ __launch_bounds__(256) void topk0_kernel(
    const float* __restrict__ x, float* __restrict__ outv, float* __restrict__ outi)
{
    const int wave = threadIdx.x >> 6;
    const int lane = threadIdx.x & 63;
    const int row  = blockIdx.x * 4 + wave;
    const float4* xr = (const float4*)(x + (size_t)row * 32000);

    u64 s0 = 0, s1 = 0;

#define K0UPD(f, b) \
    ins2_lg(s0, s1, keylg((f).x, (u32)(b)));     \
    ins2_lg(s0, s1, keylg((f).y, (u32)(b) + 1)); \
    ins2_lg(s0, s1, keylg((f).z, (u32)(b) + 2)); \
    ins2_lg(s0, s1, keylg((f).w, (u32)(b) + 3))

    // 8000 float4 per row; 125 per lane = 31*4 + 1
    int v = lane;
    for (int it = 0; it < 31; ++it, v += 256) {
        float4 t0 = xr[v];
        float4 t1 = xr[v + 64];
        float4 t2 = xr[v + 128];
        float4 t3 = xr[v + 192];
        K0UPD(t0, v * 4); K0UPD(t1, (v + 64) * 4);
        K0UPD(t2, (v + 128) * 4); K0UPD(t3, (v + 192) * 4);
    }
    { float4 t = xr[v]; K0UPD(t, v * 4); }
#undef K0UPD

    for (int m = 1; m < 64; m <<= 1) {
        u64 b0 = shx64(s0, m), b1 = shx64(s1, m);
        merge2_lg(s0, s1, b0, b1);
    }

    if (lane == 0) {
        outv[row * 2 + 0] = val_of(s0);  outv[row * 2 + 1] = val_of(s1);
        outi[row * 2 + 0] = idxf_lg(s0); outi[row * 2 + 1] = idxf_lg(s1);
    }
}

// ---------------------------------------------------------------------------
// Kernel 1: v_1 (8192 rows, 4096), top-4 smallest along last dim. Wave/row.
// ---------------------------------------------------------------------------
__global__ __launch_bounds__(256) void topk1_kernel(
    const float* __restrict__ x, float* __restrict__ outv, float* __restrict__ outi)
{
    const int wave = threadIdx.x >> 6;
    const int lane = threadIdx.x & 63;
    const int row  = blockIdx.x * 4 + wave;
    const float4* xr = (const float4*)(x + (size_t)row * 4096);

    u64 s0 = ~0ull, s1 = ~0ull, s2 = ~0ull, s3 = ~0ull;

#define K1UPD(f, b) \
    ins4_sm(s0, s1, s2, s3, keysm((f).x, (u32)(b)));     \
    ins4_sm(s0, s1, s2, s3, keysm((f).y, (u32)(b) + 1)); \
    ins4_sm(s0, s1, s2, s3, keysm((f).z, (u32)(b) + 2)); \
    ins4_sm(s0, s1, s2, s3, keysm((f).w, (u32)(b) + 3))

    // 1024 float4 per row; 16 per lane = 4*4
    int v = lane;
    for (int it = 0; it < 4; ++it, v += 256) {
        float4 t0 = xr[v];
        float4 t1 = xr[v + 64];
        float4 t2 = xr[v + 128];
        float4 t3 = xr[v + 192];
        K1UPD(t0, v * 4); K1UPD(t1, (v + 64) * 4);
        K1UPD(t2, (v + 128) * 4); K1UPD(t3, (v + 192) * 4);
    }
#undef K1UPD

    for (int m = 1; m < 64; m <<= 1) {
        u64 b0 = shx64(s0, m), b1 = shx64(s1, m);
        u64 b2 = shx64(s2, m), b3 = shx64(s3, m);
        merge4_sm(s0, s1, s2, s3, b0, b1, b2, b3);
    }

    if (lane == 0) {
        outv[row * 4 + 0] = val_of(s0);  outv[row * 4 + 1] = val_of(s1);
        outv[row * 4 + 2] = val_of(s2);  outv[row * 4 + 3] = val_of(s3);
        outi[row * 4 + 0] = idxf_sm(s0); outi[row * 4 + 1] = idxf_sm(s1);
        outi[row * 4 + 2] = idxf_sm(s2); outi[row * 4 + 3] = idxf_sm(s3);
    }
}

// ---------------------------------------------------------------------------
// TopK_2: v_2 (100000, 512), top-3 largest along dim 0 (columns).
// Phase 1: 512 blocks; block handles rpb rows x all 512 cols. Thread owns 4
// cols (float4 loads) and one row parity. State = 12 u64 regs, branchless.
// Partials: [p][3][512] u64 keys, p = blk*2 + parity (np = 1024).
// ---------------------------------------------------------------------------
__global__ __launch_bounds__(256) void topk2_p1(
    const float* __restrict__ x, u64* __restrict__ part, int rpb)
{
    const int blk = blockIdx.x;
    const int t   = threadIdx.x;
    const int h   = t >> 7;          // row parity
    const int c0  = (t & 127) * 4;   // column group
    int rbeg = blk * rpb;
    int rend = rbeg + rpb; if (rend > 100000) rend = 100000;

    u64 a[4][3];
#pragma unroll
    for (int c = 0; c < 4; ++c) { a[c][0] = 0; a[c][1] = 0; a[c][2] = 0; }

#define P1LOAD(r) (*(const float4*)(x + (size_t)(r) * 512 + c0))
#define P1UPD(f, rr) \
    ins3_lg(a[0][0], a[0][1], a[0][2], keylg((f).x, (u32)(rr))); \
    ins3_lg(a[1][0], a[1][1], a[1][2], keylg((f).y, (u32)(rr))); \
    ins3_lg(a[2][0], a[2][1], a[2][2], keylg((f).z, (u32)(rr))); \
    ins3_lg(a[3][0], a[3][1], a[3][2], keylg((f).w, (u32)(rr)))

    int r = rbeg + h;
    for (; r + 6 < rend; r += 8) {
        float4 f0 = P1LOAD(r);
        float4 f1 = P1LOAD(r + 2);
        float4 f2 = P1LOAD(r + 4);
        float4 f3 = P1LOAD(r + 6);
        P1UPD(f0, r); P1UPD(f1, r + 2); P1UPD(f2, r + 4); P1UPD(f3, r + 6);
    }
    for (; r < rend; r += 2) {
        float4 f0 = P1LOAD(r);
        P1UPD(f0, r);
    }
#undef P1LOAD
#undef P1UPD

    const int p = blk * 2 + h;
    u64* base = part + (size_t)p * 3 * 512;
#pragma unroll
    for (int k = 0; k < 3; ++k)
#pragma unroll
        for (int c = 0; c < 4; ++c)
            base[k * 512 + c0 + c] = a[c][k];
}

// Phase 2a: reduce 1024 partials -> 16 slice-partials. Thread <-> column,
// fully coalesced u64 loads. Grid = 16 slices x 2 col-blocks = 32.
__global__ __launch_bounds__(256) void topk2_p2a(
    const u64* __restrict__ part, u64* __restrict__ part2)
{
    const int b = blockIdx.x;
    const int s = b >> 1, cb = b & 1;
    const int col = cb * 256 + threadIdx.x;

    u64 a0 = 0, a1 = 0, a2 = 0;
    const u64* base = part + (size_t)s * 64 * 3 * 512;
    for (int p = 0; p < 64; p += 2) {
        const u64* q0 = base + (size_t)p * 1536;
        const u64* q1 = q0 + 1536;
        u64 x0 = q0[col], x1 = q0[512 + col], x2 = q0[1024 + col];
        u64 y0 = q1[col], y1 = q1[512 + col], y2 = q1[1024 + col];
        merge3_lg(a0, a1, a2, x0, x1, x2);
        merge3_lg(a0, a1, a2, y0, y1, y2);
    }
    part2[((size_t)s * 3 + 0) * 512 + col] = a0;
    part2[((size_t)s * 3 + 1) * 512 + col] = a1;
    part2[((size_t)s * 3 + 2) * 512 + col] = a2;
}

// Phase 2b: final merge of 16 slice-partials + decode. Thread <-> column.
__global__ __launch_bounds__(256) void topk2_p2b(
    const u64* __restrict__ part2, float* __restrict__ outv, float* __restrict__ outi)
{
    const int col = blockIdx.x * 256 + threadIdx.x;
    u64 a0 = 0, a1 = 0, a2 = 0;
    for (int s = 0; s < 16; ++s) {
        u64 x0 = part2[((size_t)s * 3 + 0) * 512 + col];
        u64 x1 = part2[((size_t)s * 3 + 1) * 512 + col];
        u64 x2 = part2[((size_t)s * 3 + 2) * 512 + col];
        merge3_lg(a0, a1, a2, x0, x1, x2);
    }
    outv[0 * 512 + col] = val_of(a0);
    outv[1 * 512 + col] = val_of(a1);
    outv[2 * 512 + col] = val_of(a2);
    outi[0 * 512 + col] = idxf_lg(a0);
    outi[1 * 512 + col] = idxf_lg(a1);
    outi[2 * 512 + col] = idxf_lg(a2);
}

// Fallback if workspace is too small (never expected): thread <-> column,
// coalesced row-major streaming, branchless.
__global__ __launch_bounds__(256) void topk2_direct(
    const float* __restrict__ x, float* __restrict__ outv, float* __restrict__ outi)
{
    const int col = blockIdx.x * 256 + threadIdx.x;
    u64 a0 = 0, a1 = 0, a2 = 0;
    for (int r = 0; r < 100000; ++r) {
        float v = x[(size_t)r * 512 + col];
        ins3_lg(a0, a1, a2, keylg(v, (u32)r));
    }
    outv[0 * 512 + col] = val_of(a0);
    outv[1 * 512 + col] = val_of(a1);
    outv[2 * 512 + col] = val_of(a2);
    outi[0 * 512 + col] = idxf_lg(a0);
    outi[1 * 512 + col] = idxf_lg(a1);
    outi[2 * 512 + col] = idxf_lg(a2);
}

extern "C" void kernel_launch(void* const* d_in, const int* in_sizes, int n_in,
                              void* d_out, int out_size, void* d_ws, size_t ws_size,
                              hipStream_t stream) {
    const float* v0 = (const float*)d_in[0];   // (4096, 32000)
    const float* v1 = (const float*)d_in[1];   // (8, 16, 64, 4096)
    const float* v2 = (const float*)d_in[2];   // (100000, 512)
    float* out = (float*)d_out;

    float* o_v4  = out;                 // (4096, 2) values
    float* o_v5  = out + 8192;          // (4096, 2) indices
    float* o_v7  = out + 16384;         // (8,16,64,4) values
    float* o_v8  = out + 49152;         // (8,16,64,4) indices
    float* o_v10 = out + 81920;         // (3, 512) values
    float* o_v11 = out + 83456;         // (3, 512) indices

    topk0_kernel<<<1024, 256, 0, stream>>>(v0, o_v4, o_v5);
    topk1_kernel<<<2048, 256, 0, stream>>>(v1, o_v7, o_v8);

    // TopK_2: np = 1024 partials (512 blocks x 2 parities) + 16 slice-partials.
    const int NB = 512;
    int rpb = (100000 + NB - 1) / NB;
    if (rpb & 1) rpb++;
    size_t need = ((size_t)NB * 2 + 16) * 3 * 512 * sizeof(u64);   // ~12.8 MB
    if (ws_size >= need) {
        u64* part  = (u64*)d_ws;
        u64* part2 = part + (size_t)NB * 2 * 3 * 512;
        topk2_p1<<<NB, 256, 0, stream>>>(v2, part, rpb);
        topk2_p2a<<<32, 256, 0, stream>>>(part, part2);
        topk2_p2b<<<2, 256, 0, stream>>>(part2, o_v10, o_v11);
    } else {
        topk2_direct<<<2, 256, 0, stream>>>(v2, o_v10, o_v11);
    }
}

// Round 4
// 190.241 us; speedup vs baseline: 4.6780x; 1.0501x over previous
//
#include <hip/hip_runtime.h>
#include <limits.h>
#include <math.h>

typedef unsigned long long u64;
typedef unsigned int u32;

// ---------------------------------------------------------------------------
// Sortable-key top-k: pack (f32 value, index) into one u64 so that plain
// unsigned max (largest-k) / min (smallest-k) implements jax.lax.top_k's
// ordering including the lowest-index-wins tie-break.
//   ord(v): monotonic f32 -> u32 (sign-flip trick), bit-exact invertible.
//   largest : key = ord(v)<<32 | ~idx   (max; tie -> larger ~idx -> smaller idx)
//   smallest: key = ord(v)<<32 |  idx   (min; tie -> smaller idx)
// Sentinels: 0 for largest (loses to any real key), ~0ull for smallest.
// ---------------------------------------------------------------------------
__device__ __forceinline__ u32 f2ord(float v) {
    u32 u = __float_as_uint(v);
    return (u & 0x80000000u) ? ~u : (u | 0x80000000u);
}
__device__ __forceinline__ float ord2f(u32 s) {
    u32 u = (s & 0x80000000u) ? (s & 0x7FFFFFFFu) : ~s;
    return __uint_as_float(u);
}
__device__ __forceinline__ u64 keylg(float v, u32 i) { return ((u64)f2ord(v) << 32) | (u64)(~i); }
__device__ __forceinline__ u64 keysm(float v, u32 i) { return ((u64)f2ord(v) << 32) | (u64)i; }
__device__ __forceinline__ float val_of(u64 k) { return ord2f((u32)(k >> 32)); }
__device__ __forceinline__ float idxf_lg(u64 k) { return (float)(~(u32)k); }
__device__ __forceinline__ float idxf_sm(u64 k) { return (float)((u32)k); }

__device__ __forceinline__ u64 mx64(u64 a, u64 b) { return a > b ? a : b; }
__device__ __forceinline__ u64 mn64(u64 a, u64 b) { return a < b ? a : b; }

// Branchless inserts into sorted lists. 2k-1 u64 min/max, no divergence.
__device__ __forceinline__ void ins2_lg(u64& s0, u64& s1, u64 k) {
    u64 t0 = mx64(s0, k), r0 = mn64(s0, k);
    s0 = t0; s1 = mx64(s1, r0);
}
__device__ __forceinline__ void ins3_lg(u64& s0, u64& s1, u64& s2, u64 k) {
    u64 t0 = mx64(s0, k), r0 = mn64(s0, k);
    u64 t1 = mx64(s1, r0), r1 = mn64(s1, r0);
    s0 = t0; s1 = t1; s2 = mx64(s2, r1);
}
__device__ __forceinline__ void ins4_sm(u64& s0, u64& s1, u64& s2, u64& s3, u64 k) {
    u64 t0 = mn64(s0, k), r0 = mx64(s0, k);
    u64 t1 = mn64(s1, r0), r1 = mx64(s1, r0);
    u64 t2 = mn64(s2, r1), r2 = mx64(s2, r1);
    s0 = t0; s1 = t1; s2 = t2; s3 = mn64(s3, r2);
}

__device__ __forceinline__ void ce_max(u64& a, u64& b) { u64 h = mx64(a, b), l = mn64(a, b); a = h; b = l; }
__device__ __forceinline__ void ce_min(u64& a, u64& b) { u64 l = mn64(a, b), h = mx64(a, b); a = l; b = h; }

// Merge two sorted lists -> best k (bitonic; branchless).
__device__ __forceinline__ void merge2_lg(u64& a0, u64& a1, u64 b0, u64 b1) {
    u64 l0 = mx64(a0, b1), l1 = mx64(a1, b0);
    a0 = mx64(l0, l1); a1 = mn64(l0, l1);
}
__device__ __forceinline__ void merge3_lg(u64& a0, u64& a1, u64& a2, u64 b0, u64 b1, u64 b2) {
    u64 l0 = mx64(a0, b2), l1 = mx64(a1, b1), l2 = mx64(a2, b0);
    ce_max(l0, l1); ce_max(l1, l2); ce_max(l0, l1);
    a0 = l0; a1 = l1; a2 = l2;
}
__device__ __forceinline__ void merge4_sm(u64& a0, u64& a1, u64& a2, u64& a3,
                                          u64 b0, u64 b1, u64 b2, u64 b3) {
    u64 l0 = mn64(a0, b3), l1 = mn64(a1, b2), l2 = mn64(a2, b1), l3 = mn64(a3, b0);
    ce_min(l0, l2); ce_min(l1, l3); ce_min(l0, l1); ce_min(l2, l3);
    a0 = l0; a1 = l1; a2 = l2; a3 = l3;
}

__device__ __forceinline__ u64 shx64(u64 v, int m) {
    u32 hi = __shfl_xor((u32)(v >> 32), m);
    u32 lo = __shfl_xor((u32)v, m);
    return ((u64)hi << 32) | (u64)lo;
}

// ---------------------------------------------------------------------------
// Megakernel: all three streaming passes in one dispatch (removes two
// inter-kernel serialization barriers; tails of the three ops pack together).
//   blocks [0, 1024)        : topk0 — v_0 (4096, 32000) top-2 largest, wave/row
//   blocks [1024, 3072)     : topk1 — v_1 (8192, 4096) top-4 smallest, wave/row
//   blocks [3072, 3584)     : topk2 phase-1 — v_2 (100000, 512) col-wise top-3
// ---------------------------------------------------------------------------
__global__ __launch_bounds__(256) void mega_kernel(
    const float* __restrict__ x0, float* __restrict__ o0v, float* __restrict__ o0i,
    const float* __restrict__ x1, float* __restrict__ o1v, float* __restrict__ o1i,
    const float* __restrict__ x2, u64* __restrict__ part, int rpb)
{
    const int bid  = blockIdx.x;
    const int wave = threadIdx.x >> 6;
    const int lane = threadIdx.x & 63;

    if (bid < 1024) {
        // ---- topk0: top-2 largest along rows of (4096, 32000) ----
        const int row = bid * 4 + wave;
        const float4* xr = (const float4*)(x0 + (size_t)row * 32000);
        u64 s0 = 0, s1 = 0;

#define K0UPD(f, b) \
        ins2_lg(s0, s1, keylg((f).x, (u32)(b)));     \
        ins2_lg(s0, s1, keylg((f).y, (u32)(b) + 1)); \
        ins2_lg(s0, s1, keylg((f).z, (u32)(b) + 2)); \
        ins2_lg(s0, s1, keylg((f).w, (u32)(b) + 3))

        int v = lane;                       // 8000 float4/row; 125/lane = 31*4+1
        for (int it = 0; it < 31; ++it, v += 256) {
            float4 t0 = xr[v];
            float4 t1 = xr[v + 64];
            float4 t2 = xr[v + 128];
            float4 t3 = xr[v + 192];
            K0UPD(t0, v * 4); K0UPD(t1, (v + 64) * 4);
            K0UPD(t2, (v + 128) * 4); K0UPD(t3, (v + 192) * 4);
        }
        { float4 t = xr[v]; K0UPD(t, v * 4); }
#undef K0UPD

        for (int m = 1; m < 64; m <<= 1) {
            u64 b0 = shx64(s0, m), b1 = shx64(s1, m);
            merge2_lg(s0, s1, b0, b1);
        }
        if (lane == 0) {
            o0v[row * 2 + 0] = val_of(s0);  o0v[row * 2 + 1] = val_of(s1);
            o0i[row * 2 + 0] = idxf_lg(s0); o0i[row * 2 + 1] = idxf_lg(s1);
        }

    } else if (bid < 3072) {
        // ---- topk1: top-4 smallest along rows of (8192, 4096) ----
        const int row = (bid - 1024) * 4 + wave;
        const float4* xr = (const float4*)(x1 + (size_t)row * 4096);
        u64 s0 = ~0ull, s1 = ~0ull, s2 = ~0ull, s3 = ~0ull;

#define K1UPD(f, b) \
        ins4_sm(s0, s1, s2, s3, keysm((f).x, (u32)(b)));     \
        ins4_sm(s0, s1, s2, s3, keysm((f).y, (u32)(b) + 1)); \
        ins4_sm(s0, s1, s2, s3, keysm((f).z, (u32)(b) + 2)); \
        ins4_sm(s0, s1, s2, s3, keysm((f).w, (u32)(b) + 3))

        int v = lane;                       // 1024 float4/row; 16/lane = 4*4
        for (int it = 0; it < 4; ++it, v += 256) {
            float4 t0 = xr[v];
            float4 t1 = xr[v + 64];
            float4 t2 = xr[v + 128];
            float4 t3 = xr[v + 192];
            K1UPD(t0, v * 4); K1UPD(t1, (v + 64) * 4);
            K1UPD(t2, (v + 128) * 4); K1UPD(t3, (v + 192) * 4);
        }
#undef K1UPD

        for (int m = 1; m < 64; m <<= 1) {
            u64 b0 = shx64(s0, m), b1 = shx64(s1, m);
            u64 b2 = shx64(s2, m), b3 = shx64(s3, m);
            merge4_sm(s0, s1, s2, s3, b0, b1, b2, b3);
        }
        if (lane == 0) {
            o1v[row * 4 + 0] = val_of(s0);  o1v[row * 4 + 1] = val_of(s1);
            o1v[row * 4 + 2] = val_of(s2);  o1v[row * 4 + 3] = val_of(s3);
            o1i[row * 4 + 0] = idxf_sm(s0); o1i[row * 4 + 1] = idxf_sm(s1);
            o1i[row * 4 + 2] = idxf_sm(s2); o1i[row * 4 + 3] = idxf_sm(s3);
        }

    } else {
        // ---- topk2 phase 1: per-block column-wise top-3 over rpb rows ----
        const int blk = bid - 3072;
        const int t   = threadIdx.x;
        const int h   = t >> 7;          // row parity
        const int c0  = (t & 127) * 4;   // column group
        int rbeg = blk * rpb;
        int rend = rbeg + rpb; if (rend > 100000) rend = 100000;

        u64 a[4][3];
#pragma unroll
        for (int c = 0; c < 4; ++c) { a[c][0] = 0; a[c][1] = 0; a[c][2] = 0; }

#define P1LOAD(r) (*(const float4*)(x2 + (size_t)(r) * 512 + c0))
#define P1UPD(f, rr) \
        ins3_lg(a[0][0], a[0][1], a[0][2], keylg((f).x, (u32)(rr))); \
        ins3_lg(a[1][0], a[1][1], a[1][2], keylg((f).y, (u32)(rr))); \
        ins3_lg(a[2][0], a[2][1], a[2][2], keylg((f).z, (u32)(rr))); \
        ins3_lg(a[3][0], a[3][1], a[3][2], keylg((f).w, (u32)(rr)))

        int r = rbeg + h;
        for (; r + 6 < rend; r += 8) {
            float4 f0 = P1LOAD(r);
            float4 f1 = P1LOAD(r + 2);
            float4 f2 = P1LOAD(r + 4);
            float4 f3 = P1LOAD(r + 6);
            P1UPD(f0, r); P1UPD(f1, r + 2); P1UPD(f2, r + 4); P1UPD(f3, r + 6);
        }
        for (; r < rend; r += 2) {
            float4 f0 = P1LOAD(r);
            P1UPD(f0, r);
        }
#undef P1LOAD
#undef P1UPD

        const int p = blk * 2 + h;       // partial id, [p][3][512] layout
        u64* base = part + (size_t)p * 3 * 512;
#pragma unroll
        for (int k = 0; k < 3; ++k)
#pragma unroll
            for (int c = 0; c < 4; ++c)
                base[k * 512 + c0 + c] = a[c][k];
    }
}

// Phase 2a: 1024 partials -> 128 slice-partials (8 partials per slice).
// Grid = 128 slices x 2 col-halves = 256 blocks; thread <-> column; all
// loads coalesced (consecutive threads, consecutive columns).
__global__ __launch_bounds__(256) void topk2_p2a(
    const u64* __restrict__ part, u64* __restrict__ part2)
{
    const int b = blockIdx.x;
    const int s = b >> 1, cb = b & 1;
    const int col = cb * 256 + threadIdx.x;

    u64 a0 = 0, a1 = 0, a2 = 0;
    const u64* base = part + (size_t)s * 8 * 1536;
#pragma unroll
    for (int p = 0; p < 8; ++p) {
        const u64* q = base + (size_t)p * 1536;
        u64 x0 = q[col], x1 = q[512 + col], x2 = q[1024 + col];
        merge3_lg(a0, a1, a2, x0, x1, x2);
    }
    part2[((size_t)s * 3 + 0) * 512 + col] = a0;
    part2[((size_t)s * 3 + 1) * 512 + col] = a1;
    part2[((size_t)s * 3 + 2) * 512 + col] = a2;
}

// Phase 2b: merge 128 slice-partials per column + decode. Wave <-> column
// (128 blocks x 4 waves): lane l merges slices l and l+64, then butterfly.
__global__ __launch_bounds__(256) void topk2_p2b(
    const u64* __restrict__ part2, float* __restrict__ outv, float* __restrict__ outi)
{
    const int wave = threadIdx.x >> 6;
    const int lane = threadIdx.x & 63;
    const int col  = blockIdx.x * 4 + wave;

    const u64* q0 = part2 + (size_t)lane * 1536 + col;
    const u64* q1 = part2 + (size_t)(lane + 64) * 1536 + col;
    u64 a0 = q0[0], a1 = q0[512], a2 = q0[1024];
    merge3_lg(a0, a1, a2, q1[0], q1[512], q1[1024]);

    for (int m = 1; m < 64; m <<= 1) {
        u64 b0 = shx64(a0, m), b1 = shx64(a1, m), b2 = shx64(a2, m);
        merge3_lg(a0, a1, a2, b0, b1, b2);
    }

    if (lane == 0) {
        outv[0 * 512 + col] = val_of(a0);
        outv[1 * 512 + col] = val_of(a1);
        outv[2 * 512 + col] = val_of(a2);
        outi[0 * 512 + col] = idxf_lg(a0);
        outi[1 * 512 + col] = idxf_lg(a1);
        outi[2 * 512 + col] = idxf_lg(a2);
    }
}

// Fallback if workspace is too small (never expected): thread <-> column,
// coalesced row-major streaming, branchless.
__global__ __launch_bounds__(256) void topk2_direct(
    const float* __restrict__ x, float* __restrict__ outv, float* __restrict__ outi)
{
    const int col = blockIdx.x * 256 + threadIdx.x;
    u64 a0 = 0, a1 = 0, a2 = 0;
    for (int r = 0; r < 100000; ++r) {
        float v = x[(size_t)r * 512 + col];
        ins3_lg(a0, a1, a2, keylg(v, (u32)r));
    }
    outv[0 * 512 + col] = val_of(a0);
    outv[1 * 512 + col] = val_of(a1);
    outv[2 * 512 + col] = val_of(a2);
    outi[0 * 512 + col] = idxf_lg(a0);
    outi[1 * 512 + col] = idxf_lg(a1);
    outi[2 * 512 + col] = idxf_lg(a2);
}

// Standalone phase-1 (used only on the tiny-workspace fallback path for the
// first two ops; keeps mega_kernel signature simple). Not normally launched.
__global__ __launch_bounds__(256) void noop_kernel() {}

extern "C" void kernel_launch(void* const* d_in, const int* in_sizes, int n_in,
                              void* d_out, int out_size, void* d_ws, size_t ws_size,
                              hipStream_t stream) {
    const float* v0 = (const float*)d_in[0];   // (4096, 32000)
    const float* v1 = (const float*)d_in[1];   // (8, 16, 64, 4096)
    const float* v2 = (const float*)d_in[2];   // (100000, 512)
    float* out = (float*)d_out;

    float* o_v4  = out;                 // (4096, 2) values
    float* o_v5  = out + 8192;          // (4096, 2) indices
    float* o_v7  = out + 16384;         // (8,16,64,4) values
    float* o_v8  = out + 49152;         // (8,16,64,4) indices
    float* o_v10 = out + 81920;         // (3, 512) values
    float* o_v11 = out + 83456;         // (3, 512) indices

    const int NB = 512;                           // phase-1 blocks
    int rpb = (100000 + NB - 1) / NB;             // 196 (even)
    if (rpb & 1) rpb++;
    size_t need = ((size_t)NB * 2 + 128) * 3 * 512 * sizeof(u64);   // ~14.2 MB

    if (ws_size >= need) {
        u64* part  = (u64*)d_ws;                       // [1024][3][512]
        u64* part2 = part + (size_t)NB * 2 * 3 * 512;  // [128][3][512]
        mega_kernel<<<3584, 256, 0, stream>>>(v0, o_v4, o_v5,
                                              v1, o_v7, o_v8,
                                              v2, part, rpb);
        topk2_p2a<<<256, 256, 0, stream>>>(part, part2);
        topk2_p2b<<<128, 256, 0, stream>>>(part2, o_v10, o_v11);
    } else {
        // Degenerate fallback: still correct, workspace-free.
        mega_kernel<<<3072, 256, 0, stream>>>(v0, o_v4, o_v5,
                                              v1, o_v7, o_v8,
                                              v2, (u64*)d_ws, 1 << 30); // p1 blocks absent
        topk2_direct<<<2, 256, 0, stream>>>(v2, o_v10, o_v11);
    }
}

// Round 5
// 178.342 us; speedup vs baseline: 4.9901x; 1.0667x over previous
//
#include <hip/hip_runtime.h>
#include <limits.h>
#include <math.h>

typedef unsigned long long u64;
typedef unsigned int u32;

// ---------------------------------------------------------------------------
// Sortable-key top-k: pack (f32 value, index) into one u64 so that plain
// unsigned max (largest-k) / min (smallest-k) implements jax.lax.top_k's
// ordering including the lowest-index-wins tie-break.
//   largest : key = ord(v)<<32 | ~idx   (max; tie -> larger ~idx -> smaller idx)
//   smallest: key = ord(v)<<32 |  idx   (min; tie -> smaller idx)
// Sentinels: 0 for largest, ~0ull for smallest.
// ---------------------------------------------------------------------------
__device__ __forceinline__ u32 f2ord(float v) {
    u32 u = __float_as_uint(v);
    return (u & 0x80000000u) ? ~u : (u | 0x80000000u);
}
__device__ __forceinline__ float ord2f(u32 s) {
    u32 u = (s & 0x80000000u) ? (s & 0x7FFFFFFFu) : ~s;
    return __uint_as_float(u);
}
__device__ __forceinline__ u64 keylg(float v, u32 i) { return ((u64)f2ord(v) << 32) | (u64)(~i); }
__device__ __forceinline__ u64 keysm(float v, u32 i) { return ((u64)f2ord(v) << 32) | (u64)i; }
__device__ __forceinline__ float val_of(u64 k) { return ord2f((u32)(k >> 32)); }
__device__ __forceinline__ float idxf_lg(u64 k) { return (float)(~(u32)k); }
__device__ __forceinline__ float idxf_sm(u64 k) { return (float)((u32)k); }

__device__ __forceinline__ u64 mx64(u64 a, u64 b) { return a > b ? a : b; }
__device__ __forceinline__ u64 mn64(u64 a, u64 b) { return a < b ? a : b; }

// Branchless inserts into sorted lists. 2k-1 u64 min/max, no divergence.
__device__ __forceinline__ void ins2_lg(u64& s0, u64& s1, u64 k) {
    u64 t0 = mx64(s0, k), r0 = mn64(s0, k);
    s0 = t0; s1 = mx64(s1, r0);
}
__device__ __forceinline__ void ins3_lg(u64& s0, u64& s1, u64& s2, u64 k) {
    u64 t0 = mx64(s0, k), r0 = mn64(s0, k);
    u64 t1 = mx64(s1, r0), r1 = mn64(s1, r0);
    s0 = t0; s1 = t1; s2 = mx64(s2, r1);
}
__device__ __forceinline__ void ins4_sm(u64& s0, u64& s1, u64& s2, u64& s3, u64 k) {
    u64 t0 = mn64(s0, k), r0 = mx64(s0, k);
    u64 t1 = mn64(s1, r0), r1 = mx64(s1, r0);
    u64 t2 = mn64(s2, r1), r2 = mx64(s2, r1);
    s0 = t0; s1 = t1; s2 = t2; s3 = mn64(s3, r2);
}

__device__ __forceinline__ void ce_max(u64& a, u64& b) { u64 h = mx64(a, b), l = mn64(a, b); a = h; b = l; }
__device__ __forceinline__ void ce_min(u64& a, u64& b) { u64 l = mn64(a, b), h = mx64(a, b); a = l; b = h; }

// Merge two sorted lists -> best k (bitonic; branchless).
__device__ __forceinline__ void merge2_lg(u64& a0, u64& a1, u64 b0, u64 b1) {
    u64 l0 = mx64(a0, b1), l1 = mx64(a1, b0);
    a0 = mx64(l0, l1); a1 = mn64(l0, l1);
}
__device__ __forceinline__ void merge3_lg(u64& a0, u64& a1, u64& a2, u64 b0, u64 b1, u64 b2) {
    u64 l0 = mx64(a0, b2), l1 = mx64(a1, b1), l2 = mx64(a2, b0);
    ce_max(l0, l1); ce_max(l1, l2); ce_max(l0, l1);
    a0 = l0; a1 = l1; a2 = l2;
}
__device__ __forceinline__ void merge4_sm(u64& a0, u64& a1, u64& a2, u64& a3,
                                          u64 b0, u64 b1, u64 b2, u64 b3) {
    u64 l0 = mn64(a0, b3), l1 = mn64(a1, b2), l2 = mn64(a2, b1), l3 = mn64(a3, b0);
    ce_min(l0, l2); ce_min(l1, l3); ce_min(l0, l1); ce_min(l2, l3);
    a0 = l0; a1 = l1; a2 = l2; a3 = l3;
}

__device__ __forceinline__ u64 shx64(u64 v, int m) {
    u32 hi = __shfl_xor((u32)(v >> 32), m);
    u32 lo = __shfl_xor((u32)v, m);
    return ((u64)hi << 32) | (u64)lo;
}

// ---------------------------------------------------------------------------
// Megakernel. LPT block order (longest blocks first, shortest last, so the
// end-of-grid tail drains with ~2.5 us quanta):
//   blocks [0, 512)      : topk2 phase-1 — ~400 KB each (longest)
//   blocks [512, 1536)   : topk0 — 4 rows/block, 512 KB each
//   blocks [1536, 3584)  : topk1 — 4 rows/block, 64 KB each (shortest, tail)
// ---------------------------------------------------------------------------
__global__ __launch_bounds__(256) void mega_kernel(
    const float* __restrict__ x0, float* __restrict__ o0v, float* __restrict__ o0i,
    const float* __restrict__ x1, float* __restrict__ o1v, float* __restrict__ o1i,
    const float* __restrict__ x2, u64* __restrict__ part, int rpb, int do_p1)
{
    const int bid  = blockIdx.x;
    const int wave = threadIdx.x >> 6;
    const int lane = threadIdx.x & 63;

    if (bid < 512) {
        // ---- topk2 phase 1: column-wise top-3 over rpb rows ----
        // Thread owns 2 columns (float2 loads; 64 lanes x 8 B = 512 B/row/wave
        // contiguous). np = 512 partials, [p][3][512] u64 layout.
        if (!do_p1) return;
        const int blk = bid;
        const int c0  = threadIdx.x * 2;
        int rbeg = blk * rpb;
        int rend = rbeg + rpb; if (rend > 100000) rend = 100000;

        u64 a0 = 0, a1 = 0, a2 = 0;   // col c0
        u64 b0 = 0, b1 = 0, b2 = 0;   // col c0+1

#define P1LOAD(r) (*(const float2*)(x2 + (size_t)(r) * 512 + c0))
#define P1UPD(f, rr) \
        ins3_lg(a0, a1, a2, keylg((f).x, (u32)(rr))); \
        ins3_lg(b0, b1, b2, keylg((f).y, (u32)(rr)))

        int r = rbeg;
        for (; r + 3 < rend; r += 4) {
            float2 f0 = P1LOAD(r);
            float2 f1 = P1LOAD(r + 1);
            float2 f2 = P1LOAD(r + 2);
            float2 f3 = P1LOAD(r + 3);
            P1UPD(f0, r); P1UPD(f1, r + 1); P1UPD(f2, r + 2); P1UPD(f3, r + 3);
        }
        for (; r < rend; ++r) {
            float2 f0 = P1LOAD(r);
            P1UPD(f0, r);
        }
#undef P1LOAD
#undef P1UPD

        u64* base = part + (size_t)blk * 1536;   // [3][512]
        base[0 * 512 + c0] = a0; base[0 * 512 + c0 + 1] = b0;
        base[1 * 512 + c0] = a1; base[1 * 512 + c0 + 1] = b1;
        base[2 * 512 + c0] = a2; base[2 * 512 + c0 + 1] = b2;

    } else if (bid < 1536) {
        // ---- topk0: top-2 largest along rows of (4096, 32000), wave/row ----
        const int row = (bid - 512) * 4 + wave;
        const float4* xr = (const float4*)(x0 + (size_t)row * 32000);
        u64 s0 = 0, s1 = 0;

#define K0UPD(f, b) \
        ins2_lg(s0, s1, keylg((f).x, (u32)(b)));     \
        ins2_lg(s0, s1, keylg((f).y, (u32)(b) + 1)); \
        ins2_lg(s0, s1, keylg((f).z, (u32)(b) + 2)); \
        ins2_lg(s0, s1, keylg((f).w, (u32)(b) + 3))

        int v = lane;                       // 8000 float4/row; 125/lane = 31*4+1
        for (int it = 0; it < 31; ++it, v += 256) {
            float4 t0 = xr[v];
            float4 t1 = xr[v + 64];
            float4 t2 = xr[v + 128];
            float4 t3 = xr[v + 192];
            K0UPD(t0, v * 4); K0UPD(t1, (v + 64) * 4);
            K0UPD(t2, (v + 128) * 4); K0UPD(t3, (v + 192) * 4);
        }
        { float4 t = xr[v]; K0UPD(t, v * 4); }
#undef K0UPD

        for (int m = 1; m < 64; m <<= 1) {
            u64 b0 = shx64(s0, m), b1 = shx64(s1, m);
            merge2_lg(s0, s1, b0, b1);
        }
        if (lane == 0) {
            o0v[row * 2 + 0] = val_of(s0);  o0v[row * 2 + 1] = val_of(s1);
            o0i[row * 2 + 0] = idxf_lg(s0); o0i[row * 2 + 1] = idxf_lg(s1);
        }

    } else {
        // ---- topk1: top-4 smallest along rows of (8192, 4096), wave/row ----
        const int row = (bid - 1536) * 4 + wave;
        const float4* xr = (const float4*)(x1 + (size_t)row * 4096);
        u64 s0 = ~0ull, s1 = ~0ull, s2 = ~0ull, s3 = ~0ull;

#define K1UPD(f, b) \
        ins4_sm(s0, s1, s2, s3, keysm((f).x, (u32)(b)));     \
        ins4_sm(s0, s1, s2, s3, keysm((f).y, (u32)(b) + 1)); \
        ins4_sm(s0, s1, s2, s3, keysm((f).z, (u32)(b) + 2)); \
        ins4_sm(s0, s1, s2, s3, keysm((f).w, (u32)(b) + 3))

        int v = lane;                       // 1024 float4/row; 16/lane = 4*4
        for (int it = 0; it < 4; ++it, v += 256) {
            float4 t0 = xr[v];
            float4 t1 = xr[v + 64];
            float4 t2 = xr[v + 128];
            float4 t3 = xr[v + 192];
            K1UPD(t0, v * 4); K1UPD(t1, (v + 64) * 4);
            K1UPD(t2, (v + 128) * 4); K1UPD(t3, (v + 192) * 4);
        }
#undef K1UPD

        for (int m = 1; m < 64; m <<= 1) {
            u64 b0 = shx64(s0, m), b1 = shx64(s1, m);
            u64 b2 = shx64(s2, m), b3 = shx64(s3, m);
            merge4_sm(s0, s1, s2, s3, b0, b1, b2, b3);
        }
        if (lane == 0) {
            o1v[row * 4 + 0] = val_of(s0);  o1v[row * 4 + 1] = val_of(s1);
            o1v[row * 4 + 2] = val_of(s2);  o1v[row * 4 + 3] = val_of(s3);
            o1i[row * 4 + 0] = idxf_sm(s0); o1i[row * 4 + 1] = idxf_sm(s1);
            o1i[row * 4 + 2] = idxf_sm(s2); o1i[row * 4 + 3] = idxf_sm(s3);
        }
    }
}

// Single-launch reduction: merge 512 partials per column + decode.
// Wave <-> column (128 blocks x 4 waves): lane l merges partials l+64j,
// then 6-step butterfly. ~6.3 MB read, mostly L2-resident.
__global__ __launch_bounds__(256) void topk2_reduce(
    const u64* __restrict__ part, float* __restrict__ outv, float* __restrict__ outi)
{
    const int wave = threadIdx.x >> 6;
    const int lane = threadIdx.x & 63;
    const int col  = blockIdx.x * 4 + wave;

    u64 a0 = 0, a1 = 0, a2 = 0;
#pragma unroll
    for (int j = 0; j < 8; ++j) {
        const u64* q = part + (size_t)(lane + 64 * j) * 1536 + col;
        merge3_lg(a0, a1, a2, q[0], q[512], q[1024]);
    }
    for (int m = 1; m < 64; m <<= 1) {
        u64 b0 = shx64(a0, m), b1 = shx64(a1, m), b2 = shx64(a2, m);
        merge3_lg(a0, a1, a2, b0, b1, b2);
    }

    if (lane == 0) {
        outv[0 * 512 + col] = val_of(a0);
        outv[1 * 512 + col] = val_of(a1);
        outv[2 * 512 + col] = val_of(a2);
        outi[0 * 512 + col] = idxf_lg(a0);
        outi[1 * 512 + col] = idxf_lg(a1);
        outi[2 * 512 + col] = idxf_lg(a2);
    }
}

// Fallback if workspace is too small (never expected): thread <-> column,
// coalesced row-major streaming, branchless.
__global__ __launch_bounds__(256) void topk2_direct(
    const float* __restrict__ x, float* __restrict__ outv, float* __restrict__ outi)
{
    const int col = blockIdx.x * 256 + threadIdx.x;
    u64 a0 = 0, a1 = 0, a2 = 0;
    for (int r = 0; r < 100000; ++r) {
        float v = x[(size_t)r * 512 + col];
        ins3_lg(a0, a1, a2, keylg(v, (u32)r));
    }
    outv[0 * 512 + col] = val_of(a0);
    outv[1 * 512 + col] = val_of(a1);
    outv[2 * 512 + col] = val_of(a2);
    outi[0 * 512 + col] = idxf_lg(a0);
    outi[1 * 512 + col] = idxf_lg(a1);
    outi[2 * 512 + col] = idxf_lg(a2);
}

extern "C" void kernel_launch(void* const* d_in, const int* in_sizes, int n_in,
                              void* d_out, int out_size, void* d_ws, size_t ws_size,
                              hipStream_t stream) {
    const float* v0 = (const float*)d_in[0];   // (4096, 32000)
    const float* v1 = (const float*)d_in[1];   // (8, 16, 64, 4096)
    const float* v2 = (const float*)d_in[2];   // (100000, 512)
    float* out = (float*)d_out;

    float* o_v4  = out;                 // (4096, 2) values
    float* o_v5  = out + 8192;          // (4096, 2) indices
    float* o_v7  = out + 16384;         // (8,16,64,4) values
    float* o_v8  = out + 49152;         // (8,16,64,4) indices
    float* o_v10 = out + 81920;         // (3, 512) values
    float* o_v11 = out + 83456;         // (3, 512) indices

    const int NB = 512;                           // phase-1 blocks / partials
    int rpb = (100000 + NB - 1) / NB;             // 196
    size_t need = (size_t)NB * 3 * 512 * sizeof(u64);   // ~6.3 MB

    if (ws_size >= need) {
        u64* part = (u64*)d_ws;                    // [512][3][512]
        mega_kernel<<<3584, 256, 0, stream>>>(v0, o_v4, o_v5,
                                              v1, o_v7, o_v8,
                                              v2, part, rpb, 1);
        topk2_reduce<<<128, 256, 0, stream>>>(part, o_v10, o_v11);
    } else {
        mega_kernel<<<3584, 256, 0, stream>>>(v0, o_v4, o_v5,
                                              v1, o_v7, o_v8,
                                              v2, (u64*)d_ws, rpb, 0);
        topk2_direct<<<2, 256, 0, stream>>>(v2, o_v10, o_v11);
    }
}

// Round 6
// 171.074 us; speedup vs baseline: 5.2021x; 1.0425x over previous
//
#include <hip/hip_runtime.h>
#include <limits.h>
#include <math.h>

typedef unsigned long long u64;
typedef unsigned int u32;

// ---------------------------------------------------------------------------
// Sortable-key top-k: pack (f32 value, index) into one u64 so that plain
// unsigned max (largest-k) / min (smallest-k) implements jax.lax.top_k's
// ordering including the lowest-index-wins tie-break.
//   largest : key = ord(v)<<32 | ~idx   (max; tie -> larger ~idx -> smaller idx)
//   smallest: key = ord(v)<<32 |  idx   (min; tie -> smaller idx)
// Sentinels: 0 for largest, ~0ull for smallest.
// ---------------------------------------------------------------------------
__device__ __forceinline__ u32 f2ord(float v) {
    u32 u = __float_as_uint(v);
    // branchless: ord = u ^ ( (int(u)>>31) | 0x80000000 )
    return u ^ (((u32)((int)u >> 31)) | 0x80000000u);
}
__device__ __forceinline__ float ord2f(u32 s) {
    u32 u = (s & 0x80000000u) ? (s & 0x7FFFFFFFu) : ~s;
    return __uint_as_float(u);
}
__device__ __forceinline__ u64 keylg(float v, u32 i) { return ((u64)f2ord(v) << 32) | (u64)(~i); }
__device__ __forceinline__ u64 keysm(float v, u32 i) { return ((u64)f2ord(v) << 32) | (u64)i; }
__device__ __forceinline__ float val_of(u64 k) { return ord2f((u32)(k >> 32)); }
__device__ __forceinline__ float idxf_lg(u64 k) { return (float)(~(u32)k); }
__device__ __forceinline__ float idxf_sm(u64 k) { return (float)((u32)k); }

__device__ __forceinline__ u64 mx64(u64 a, u64 b) { return a > b ? a : b; }
__device__ __forceinline__ u64 mn64(u64 a, u64 b) { return a < b ? a : b; }

// Branchless insert into best-first sorted 3-list (largest).
__device__ __forceinline__ void ins3_lg(u64& s0, u64& s1, u64& s2, u64 k) {
    u64 t0 = mx64(s0, k), r0 = mn64(s0, k);
    u64 t1 = mx64(s1, r0), r1 = mn64(s1, r0);
    s0 = t0; s1 = t1; s2 = mx64(s2, r1);
}

__device__ __forceinline__ void ce_max(u64& a, u64& b) { u64 h = mx64(a, b), l = mn64(a, b); a = h; b = l; }
__device__ __forceinline__ void ce_min(u64& a, u64& b) { u64 l = mn64(a, b), h = mx64(a, b); a = l; b = h; }

// Merge two desc-sorted 2-lists -> best 2 (into A). 4 ops, chain 2.
__device__ __forceinline__ void merge2_lg(u64& a0, u64& a1, u64 b0, u64 b1) {
    u64 l0 = mx64(a0, b1), l1 = mx64(a1, b0);
    a0 = mx64(l0, l1); a1 = mn64(l0, l1);
}
__device__ __forceinline__ void merge3_lg(u64& a0, u64& a1, u64& a2, u64 b0, u64 b1, u64 b2) {
    u64 l0 = mx64(a0, b2), l1 = mx64(a1, b1), l2 = mx64(a2, b0);
    ce_max(l0, l1); ce_max(l1, l2); ce_max(l0, l1);
    a0 = l0; a1 = l1; a2 = l2;
}
// Merge asc-sorted 4-list B into asc state A -> best(smallest) 4. 8 ops.
__device__ __forceinline__ void merge4_sm(u64& a0, u64& a1, u64& a2, u64& a3,
                                          u64 b0, u64 b1, u64 b2, u64 b3) {
    u64 l0 = mn64(a0, b3), l1 = mn64(a1, b2), l2 = mn64(a2, b1), l3 = mn64(a3, b0);
    ce_min(l0, l2); ce_min(l1, l3); ce_min(l0, l1); ce_min(l2, l3);
    a0 = l0; a1 = l1; a2 = l2; a3 = l3;
}

__device__ __forceinline__ u64 shx64(u64 v, int m) {
    u32 hi = __shfl_xor((u32)(v >> 32), m);
    u32 lo = __shfl_xor((u32)v, m);
    return ((u64)hi << 32) | (u64)lo;
}

// Tree top-2 (largest) of a float4 -> desc 2-list (o0 >= o1). 4+4 ops, chain 3.
__device__ __forceinline__ void top2of4_lg(float4 f, u32 b, u64& o0, u64& o1) {
    u64 k0 = keylg(f.x, b), k1 = keylg(f.y, b + 1);
    u64 k2 = keylg(f.z, b + 2), k3 = keylg(f.w, b + 3);
    u64 h0 = mx64(k0, k1), l0 = mn64(k0, k1);
    u64 h1 = mx64(k2, k3), l1 = mn64(k2, k3);
    u64 m0 = mx64(h0, l1), m1 = mx64(l0, h1);
    o0 = mx64(m0, m1); o1 = mn64(m0, m1);
}

// Full asc sort of a float4's 4 keys (smallest). 10 ops (2+2 merge network).
__device__ __forceinline__ void sort4_sm(float4 f, u32 bse,
                                         u64& b0, u64& b1, u64& b2, u64& b3) {
    u64 k0 = keysm(f.x, bse), k1 = keysm(f.y, bse + 1);
    u64 k2 = keysm(f.z, bse + 2), k3 = keysm(f.w, bse + 3);
    u64 p0 = mn64(k0, k1), p1 = mx64(k0, k1);
    u64 q0 = mn64(k2, k3), q1 = mx64(k2, k3);
    b0 = mn64(p0, q0); u64 t = mx64(p0, q0);
    b3 = mx64(p1, q1); u64 u = mn64(p1, q1);
    b1 = mn64(t, u); b2 = mx64(t, u);
}

// ---------------------------------------------------------------------------
// Megakernel, LPT order (longest blocks first):
//   blocks [0, 1024)     : topk0 — 4 rows/block, 512 KB each (longest)
//   blocks [1024, 1536)  : topk2 phase-1 — ~392 KB each
//   blocks [1536, 3584)  : topk1 — 4 rows/block, 64 KB each (tail filler)
// ---------------------------------------------------------------------------
__global__ __launch_bounds__(256) void mega_kernel(
    const float* __restrict__ x0, float* __restrict__ o0v, float* __restrict__ o0i,
    const float* __restrict__ x1, float* __restrict__ o1v, float* __restrict__ o1i,
    const float* __restrict__ x2, u64* __restrict__ part, int rpb, int do_p1)
{
    const int bid  = blockIdx.x;
    const int wave = threadIdx.x >> 6;
    const int lane = threadIdx.x & 63;

    if (bid < 1024) {
        // ---- topk0: top-2 largest along rows of (4096, 32000), wave/row ----
        // Dual accumulators (even/odd loads) break the serial state chain.
        const int row = bid * 4 + wave;
        const float4* xr = (const float4*)(x0 + (size_t)row * 32000);
        u64 sA0 = 0, sA1 = 0, sB0 = 0, sB1 = 0;

        int v = lane;                       // 8000 float4/row; 125/lane = 31*4+1
        for (int it = 0; it < 31; ++it, v += 256) {
            float4 t0 = xr[v];
            float4 t1 = xr[v + 64];
            float4 t2 = xr[v + 128];
            float4 t3 = xr[v + 192];
            u64 w0, w1;
            top2of4_lg(t0, (u32)(v * 4),         w0, w1); merge2_lg(sA0, sA1, w0, w1);
            top2of4_lg(t1, (u32)((v + 64) * 4),  w0, w1); merge2_lg(sB0, sB1, w0, w1);
            top2of4_lg(t2, (u32)((v + 128) * 4), w0, w1); merge2_lg(sA0, sA1, w0, w1);
            top2of4_lg(t3, (u32)((v + 192) * 4), w0, w1); merge2_lg(sB0, sB1, w0, w1);
        }
        {   // tail: v = lane + 7936 < 8000
            float4 t = xr[v];
            u64 w0, w1;
            top2of4_lg(t, (u32)(v * 4), w0, w1); merge2_lg(sA0, sA1, w0, w1);
        }
        merge2_lg(sA0, sA1, sB0, sB1);

        for (int m = 1; m < 64; m <<= 1) {
            u64 b0 = shx64(sA0, m), b1 = shx64(sA1, m);
            merge2_lg(sA0, sA1, b0, b1);
        }
        if (lane == 0) {
            o0v[row * 2 + 0] = val_of(sA0);  o0v[row * 2 + 1] = val_of(sA1);
            o0i[row * 2 + 0] = idxf_lg(sA0); o0i[row * 2 + 1] = idxf_lg(sA1);
        }

    } else if (bid < 1536) {
        // ---- topk2 phase 1: column-wise top-3 over rpb rows ----
        // Thread owns 2 columns (float2); 8 rows in flight (64 B/lane).
        if (!do_p1) return;
        const int blk = bid - 1024;
        const int c0  = threadIdx.x * 2;
        int rbeg = blk * rpb;
        int rend = rbeg + rpb; if (rend > 100000) rend = 100000;

        u64 a0 = 0, a1 = 0, a2 = 0;   // col c0
        u64 b0 = 0, b1 = 0, b2 = 0;   // col c0+1

#define P1LOAD(r) (*(const float2*)(x2 + (size_t)(r) * 512 + c0))
#define P1UPD(f, rr) \
        ins3_lg(a0, a1, a2, keylg((f).x, (u32)(rr))); \
        ins3_lg(b0, b1, b2, keylg((f).y, (u32)(rr)))

        int r = rbeg;
        for (; r + 7 < rend; r += 8) {
            float2 f0 = P1LOAD(r);
            float2 f1 = P1LOAD(r + 1);
            float2 f2 = P1LOAD(r + 2);
            float2 f3 = P1LOAD(r + 3);
            float2 f4 = P1LOAD(r + 4);
            float2 f5 = P1LOAD(r + 5);
            float2 f6 = P1LOAD(r + 6);
            float2 f7 = P1LOAD(r + 7);
            P1UPD(f0, r);     P1UPD(f1, r + 1); P1UPD(f2, r + 2); P1UPD(f3, r + 3);
            P1UPD(f4, r + 4); P1UPD(f5, r + 5); P1UPD(f6, r + 6); P1UPD(f7, r + 7);
        }
        for (; r < rend; ++r) {
            float2 f0 = P1LOAD(r);
            P1UPD(f0, r);
        }
#undef P1LOAD
#undef P1UPD

        u64* base = part + (size_t)blk * 1536;   // [3][512]
        base[0 * 512 + c0] = a0; base[0 * 512 + c0 + 1] = b0;
        base[1 * 512 + c0] = a1; base[1 * 512 + c0 + 1] = b1;
        base[2 * 512 + c0] = a2; base[2 * 512 + c0 + 1] = b2;

    } else {
        // ---- topk1: top-4 smallest along rows of (8192, 4096), wave/row ----
        // Tree form: full sort-4 per float4 (10 ops), one state merge (8 ops).
        const int row = (bid - 1536) * 4 + wave;
        const float4* xr = (const float4*)(x1 + (size_t)row * 4096);
        u64 s0 = ~0ull, s1 = ~0ull, s2 = ~0ull, s3 = ~0ull;

#define K1UPD(f, b) { u64 c0_, c1_, c2_, c3_;                      \
        sort4_sm((f), (u32)(b), c0_, c1_, c2_, c3_);               \
        merge4_sm(s0, s1, s2, s3, c0_, c1_, c2_, c3_); }

        int v = lane;                       // 1024 float4/row; 16/lane = 4*4
        for (int it = 0; it < 4; ++it, v += 256) {
            float4 t0 = xr[v];
            float4 t1 = xr[v + 64];
            float4 t2 = xr[v + 128];
            float4 t3 = xr[v + 192];
            K1UPD(t0, v * 4);
            K1UPD(t1, (v + 64) * 4);
            K1UPD(t2, (v + 128) * 4);
            K1UPD(t3, (v + 192) * 4);
        }
#undef K1UPD

        for (int m = 1; m < 64; m <<= 1) {
            u64 b0 = shx64(s0, m), b1 = shx64(s1, m);
            u64 b2 = shx64(s2, m), b3 = shx64(s3, m);
            merge4_sm(s0, s1, s2, s3, b0, b1, b2, b3);
        }
        if (lane == 0) {
            o1v[row * 4 + 0] = val_of(s0);  o1v[row * 4 + 1] = val_of(s1);
            o1v[row * 4 + 2] = val_of(s2);  o1v[row * 4 + 3] = val_of(s3);
            o1i[row * 4 + 0] = idxf_sm(s0); o1i[row * 4 + 1] = idxf_sm(s1);
            o1i[row * 4 + 2] = idxf_sm(s2); o1i[row * 4 + 3] = idxf_sm(s3);
        }
    }
}

// Single-launch reduction: merge 512 partials per column + decode.
// Wave <-> column (128 blocks x 4 waves): lane l merges partials l+64j,
// then 6-step butterfly. ~6.3 MB read.
__global__ __launch_bounds__(256) void topk2_reduce(
    const u64* __restrict__ part, float* __restrict__ outv, float* __restrict__ outi)
{
    const int wave = threadIdx.x >> 6;
    const int lane = threadIdx.x & 63;
    const int col  = blockIdx.x * 4 + wave;

    u64 a0 = 0, a1 = 0, a2 = 0;
#pragma unroll
    for (int j = 0; j < 8; ++j) {
        const u64* q = part + (size_t)(lane + 64 * j) * 1536 + col;
        merge3_lg(a0, a1, a2, q[0], q[512], q[1024]);
    }
    for (int m = 1; m < 64; m <<= 1) {
        u64 b0 = shx64(a0, m), b1 = shx64(a1, m), b2 = shx64(a2, m);
        merge3_lg(a0, a1, a2, b0, b1, b2);
    }

    if (lane == 0) {
        outv[0 * 512 + col] = val_of(a0);
        outv[1 * 512 + col] = val_of(a1);
        outv[2 * 512 + col] = val_of(a2);
        outi[0 * 512 + col] = idxf_lg(a0);
        outi[1 * 512 + col] = idxf_lg(a1);
        outi[2 * 512 + col] = idxf_lg(a2);
    }
}

// Fallback if workspace is too small (never expected): thread <-> column,
// coalesced row-major streaming, branchless.
__global__ __launch_bounds__(256) void topk2_direct(
    const float* __restrict__ x, float* __restrict__ outv, float* __restrict__ outi)
{
    const int col = blockIdx.x * 256 + threadIdx.x;
    u64 a0 = 0, a1 = 0, a2 = 0;
    for (int r = 0; r < 100000; ++r) {
        float v = x[(size_t)r * 512 + col];
        ins3_lg(a0, a1, a2, keylg(v, (u32)r));
    }
    outv[0 * 512 + col] = val_of(a0);
    outv[1 * 512 + col] = val_of(a1);
    outv[2 * 512 + col] = val_of(a2);
    outi[0 * 512 + col] = idxf_lg(a0);
    outi[1 * 512 + col] = idxf_lg(a1);
    outi[2 * 512 + col] = idxf_lg(a2);
}

extern "C" void kernel_launch(void* const* d_in, const int* in_sizes, int n_in,
                              void* d_out, int out_size, void* d_ws, size_t ws_size,
                              hipStream_t stream) {
    const float* v0 = (const float*)d_in[0];   // (4096, 32000)
    const float* v1 = (const float*)d_in[1];   // (8, 16, 64, 4096)
    const float* v2 = (const float*)d_in[2];   // (100000, 512)
    float* out = (float*)d_out;

    float* o_v4  = out;                 // (4096, 2) values
    float* o_v5  = out + 8192;          // (4096, 2) indices
    float* o_v7  = out + 16384;         // (8,16,64,4) values
    float* o_v8  = out + 49152;         // (8,16,64,4) indices
    float* o_v10 = out + 81920;         // (3, 512) values
    float* o_v11 = out + 83456;         // (3, 512) indices

    const int NB = 512;                           // phase-1 blocks / partials
    int rpb = (100000 + NB - 1) / NB;             // 196
    size_t need = (size_t)NB * 3 * 512 * sizeof(u64);   // ~6.3 MB

    if (ws_size >= need) {
        u64* part = (u64*)d_ws;                    // [512][3][512]
        mega_kernel<<<3584, 256, 0, stream>>>(v0, o_v4, o_v5,
                                              v1, o_v7, o_v8,
                                              v2, part, rpb, 1);
        topk2_reduce<<<128, 256, 0, stream>>>(part, o_v10, o_v11);
    } else {
        mega_kernel<<<3584, 256, 0, stream>>>(v0, o_v4, o_v5,
                                              v1, o_v7, o_v8,
                                              v2, (u64*)d_ws, rpb, 0);
        topk2_direct<<<2, 256, 0, stream>>>(v2, o_v10, o_v11);
    }
}

// Round 8
// 154.420 us; speedup vs baseline: 5.7631x; 1.1078x over previous
//
#include <hip/hip_runtime.h>
#include <limits.h>
#include <math.h>

typedef unsigned long long u64;
typedef unsigned int u32;
typedef float f32x4 __attribute__((ext_vector_type(4)));
typedef float f32x2 __attribute__((ext_vector_type(2)));

// ---------------------------------------------------------------------------
// Sortable-key top-k: pack (f32 value, index) into one u64 so that plain
// unsigned max (largest-k) / min (smallest-k) implements jax.lax.top_k's
// ordering including the lowest-index-wins tie-break.
//   largest : key = ord(v)<<32 | ~idx   (max; tie -> larger ~idx -> smaller idx)
//   smallest: key = ord(v)<<32 |  idx   (min; tie -> smaller idx)
// Sentinels: 0 for largest, ~0ull for smallest.
// ---------------------------------------------------------------------------
__device__ __forceinline__ u32 f2ord(float v) {
    u32 u = __float_as_uint(v);
    return u ^ (((u32)((int)u >> 31)) | 0x80000000u);
}
__device__ __forceinline__ float ord2f(u32 s) {
    u32 u = (s & 0x80000000u) ? (s & 0x7FFFFFFFu) : ~s;
    return __uint_as_float(u);
}
__device__ __forceinline__ u64 keylg(float v, u32 i) { return ((u64)f2ord(v) << 32) | (u64)(~i); }
__device__ __forceinline__ u64 keysm(float v, u32 i) { return ((u64)f2ord(v) << 32) | (u64)i; }
__device__ __forceinline__ float val_of(u64 k) { return ord2f((u32)(k >> 32)); }
__device__ __forceinline__ float idxf_lg(u64 k) { return (float)(~(u32)k); }
__device__ __forceinline__ float idxf_sm(u64 k) { return (float)((u32)k); }

__device__ __forceinline__ u64 mx64(u64 a, u64 b) { return a > b ? a : b; }
__device__ __forceinline__ u64 mn64(u64 a, u64 b) { return a < b ? a : b; }

// Branchless insert into best-first sorted 3-list (largest).
__device__ __forceinline__ void ins3_lg(u64& s0, u64& s1, u64& s2, u64 k) {
    u64 t0 = mx64(s0, k), r0 = mn64(s0, k);
    u64 t1 = mx64(s1, r0), r1 = mn64(s1, r0);
    s0 = t0; s1 = t1; s2 = mx64(s2, r1);
}

__device__ __forceinline__ void ce_max(u64& a, u64& b) { u64 h = mx64(a, b), l = mn64(a, b); a = h; b = l; }
__device__ __forceinline__ void ce_min(u64& a, u64& b) { u64 l = mn64(a, b), h = mx64(a, b); a = l; b = h; }

// Merge two desc-sorted 2-lists -> best 2 (into A). 4 ops, chain 2.
__device__ __forceinline__ void merge2_lg(u64& a0, u64& a1, u64 b0, u64 b1) {
    u64 l0 = mx64(a0, b1), l1 = mx64(a1, b0);
    a0 = mx64(l0, l1); a1 = mn64(l0, l1);
}
__device__ __forceinline__ void merge3_lg(u64& a0, u64& a1, u64& a2, u64 b0, u64 b1, u64 b2) {
    u64 l0 = mx64(a0, b2), l1 = mx64(a1, b1), l2 = mx64(a2, b0);
    ce_max(l0, l1); ce_max(l1, l2); ce_max(l0, l1);
    a0 = l0; a1 = l1; a2 = l2;
}
// Merge asc-sorted 4-list B into asc state A -> best(smallest) 4. 8 ops.
__device__ __forceinline__ void merge4_sm(u64& a0, u64& a1, u64& a2, u64& a3,
                                          u64 b0, u64 b1, u64 b2, u64 b3) {
    u64 l0 = mn64(a0, b3), l1 = mn64(a1, b2), l2 = mn64(a2, b1), l3 = mn64(a3, b0);
    ce_min(l0, l2); ce_min(l1, l3); ce_min(l0, l1); ce_min(l2, l3);
    a0 = l0; a1 = l1; a2 = l2; a3 = l3;
}

__device__ __forceinline__ u64 shx64(u64 v, int m) {
    u32 hi = __shfl_xor((u32)(v >> 32), m);
    u32 lo = __shfl_xor((u32)v, m);
    return ((u64)hi << 32) | (u64)lo;
}

// Tree top-2 (largest) of 4 values -> desc 2-list (o0 >= o1). chain 3.
__device__ __forceinline__ void top2of4_lg(f32x4 f, u32 b, u64& o0, u64& o1) {
    u64 k0 = keylg(f.x, b), k1 = keylg(f.y, b + 1);
    u64 k2 = keylg(f.z, b + 2), k3 = keylg(f.w, b + 3);
    u64 h0 = mx64(k0, k1), l0 = mn64(k0, k1);
    u64 h1 = mx64(k2, k3), l1 = mn64(k2, k3);
    u64 m0 = mx64(h0, l1), m1 = mx64(l0, h1);
    o0 = mx64(m0, m1); o1 = mn64(m0, m1);
}

// Full asc sort of 4 keys (smallest). 10 ops (2+2 merge network).
__device__ __forceinline__ void sort4_sm(f32x4 f, u32 bse,
                                         u64& b0, u64& b1, u64& b2, u64& b3) {
    u64 k0 = keysm(f.x, bse), k1 = keysm(f.y, bse + 1);
    u64 k2 = keysm(f.z, bse + 2), k3 = keysm(f.w, bse + 3);
    u64 p0 = mn64(k0, k1), p1 = mx64(k0, k1);
    u64 q0 = mn64(k2, k3), q1 = mx64(k2, k3);
    b0 = mn64(p0, q0); u64 t = mx64(p0, q0);
    b3 = mx64(p1, q1); u64 u = mn64(p1, q1);
    b1 = mn64(t, u); b2 = mx64(t, u);
}

#define NTL4(p) __builtin_nontemporal_load((const f32x4*)(p))
#define NTL2(p) __builtin_nontemporal_load((const f32x2*)(p))

// ---------------------------------------------------------------------------
// Megakernel, LPT order (longest blocks first):
//   blocks [0, 1024)     : topk0 — 4 rows/block, 512 KB each (longest)
//   blocks [1024, 1536)  : topk2 phase-1 — ~392 KB each
//   blocks [1536, 3584)  : topk1 — 4 rows/block, 64 KB each (tail filler)
// All input-stream loads are nontemporal (single-use; keep L2 for partials).
// ---------------------------------------------------------------------------
__global__ __launch_bounds__(256) void mega_kernel(
    const float* __restrict__ x0, float* __restrict__ o0v, float* __restrict__ o0i,
    const float* __restrict__ x1, float* __restrict__ o1v, float* __restrict__ o1i,
    const float* __restrict__ x2, u64* __restrict__ part, int rpb, int do_p1)
{
    const int bid  = blockIdx.x;
    const int wave = threadIdx.x >> 6;
    const int lane = threadIdx.x & 63;

    if (bid < 1024) {
        // ---- topk0: top-2 largest along rows of (4096, 32000), wave/row ----
        // 8 float4 in flight (128 B/lane); dual accumulators A/B.
        const int row = bid * 4 + wave;
        const f32x4* xr = (const f32x4*)(x0 + (size_t)row * 32000);
        u64 sA0 = 0, sA1 = 0, sB0 = 0, sB1 = 0;

        // 8000 float4/row; 125/lane = 15*8 + 5
        int v = lane;
        for (int it = 0; it < 15; ++it, v += 512) {
            f32x4 t0 = NTL4(&xr[v]);
            f32x4 t1 = NTL4(&xr[v + 64]);
            f32x4 t2 = NTL4(&xr[v + 128]);
            f32x4 t3 = NTL4(&xr[v + 192]);
            f32x4 t4 = NTL4(&xr[v + 256]);
            f32x4 t5 = NTL4(&xr[v + 320]);
            f32x4 t6 = NTL4(&xr[v + 384]);
            f32x4 t7 = NTL4(&xr[v + 448]);
            u64 w0, w1;
            top2of4_lg(t0, (u32)(v * 4),         w0, w1); merge2_lg(sA0, sA1, w0, w1);
            top2of4_lg(t1, (u32)((v + 64) * 4),  w0, w1); merge2_lg(sB0, sB1, w0, w1);
            top2of4_lg(t2, (u32)((v + 128) * 4), w0, w1); merge2_lg(sA0, sA1, w0, w1);
            top2of4_lg(t3, (u32)((v + 192) * 4), w0, w1); merge2_lg(sB0, sB1, w0, w1);
            top2of4_lg(t4, (u32)((v + 256) * 4), w0, w1); merge2_lg(sA0, sA1, w0, w1);
            top2of4_lg(t5, (u32)((v + 320) * 4), w0, w1); merge2_lg(sB0, sB1, w0, w1);
            top2of4_lg(t6, (u32)((v + 384) * 4), w0, w1); merge2_lg(sA0, sA1, w0, w1);
            top2of4_lg(t7, (u32)((v + 448) * 4), w0, w1); merge2_lg(sB0, sB1, w0, w1);
        }
        {   // tail: 5 more (v = lane + 7680; max 7999)
            f32x4 t0 = NTL4(&xr[v]);
            f32x4 t1 = NTL4(&xr[v + 64]);
            f32x4 t2 = NTL4(&xr[v + 128]);
            f32x4 t3 = NTL4(&xr[v + 192]);
            f32x4 t4 = NTL4(&xr[v + 256]);
            u64 w0, w1;
            top2of4_lg(t0, (u32)(v * 4),         w0, w1); merge2_lg(sA0, sA1, w0, w1);
            top2of4_lg(t1, (u32)((v + 64) * 4),  w0, w1); merge2_lg(sB0, sB1, w0, w1);
            top2of4_lg(t2, (u32)((v + 128) * 4), w0, w1); merge2_lg(sA0, sA1, w0, w1);
            top2of4_lg(t3, (u32)((v + 192) * 4), w0, w1); merge2_lg(sB0, sB1, w0, w1);
            top2of4_lg(t4, (u32)((v + 256) * 4), w0, w1); merge2_lg(sA0, sA1, w0, w1);
        }
        merge2_lg(sA0, sA1, sB0, sB1);

        for (int m = 1; m < 64; m <<= 1) {
            u64 b0 = shx64(sA0, m), b1 = shx64(sA1, m);
            merge2_lg(sA0, sA1, b0, b1);
        }
        if (lane == 0) {
            o0v[row * 2 + 0] = val_of(sA0);  o0v[row * 2 + 1] = val_of(sA1);
            o0i[row * 2 + 0] = idxf_lg(sA0); o0i[row * 2 + 1] = idxf_lg(sA1);
        }

    } else if (bid < 1536) {
        // ---- topk2 phase 1: column-wise top-3 over rpb rows ----
        // Thread owns 2 columns (float2); 8 rows in flight (64 B/lane).
        if (!do_p1) return;
        const int blk = bid - 1024;
        const int c0  = threadIdx.x * 2;
        int rbeg = blk * rpb;
        int rend = rbeg + rpb; if (rend > 100000) rend = 100000;

        u64 a0 = 0, a1 = 0, a2 = 0;   // col c0
        u64 b0 = 0, b1 = 0, b2 = 0;   // col c0+1

#define P1LOAD(r) NTL2(x2 + (size_t)(r) * 512 + c0)
#define P1UPD(f, rr) \
        ins3_lg(a0, a1, a2, keylg((f).x, (u32)(rr))); \
        ins3_lg(b0, b1, b2, keylg((f).y, (u32)(rr)))

        int r = rbeg;
        for (; r + 7 < rend; r += 8) {
            f32x2 f0 = P1LOAD(r);
            f32x2 f1 = P1LOAD(r + 1);
            f32x2 f2 = P1LOAD(r + 2);
            f32x2 f3 = P1LOAD(r + 3);
            f32x2 f4 = P1LOAD(r + 4);
            f32x2 f5 = P1LOAD(r + 5);
            f32x2 f6 = P1LOAD(r + 6);
            f32x2 f7 = P1LOAD(r + 7);
            P1UPD(f0, r);     P1UPD(f1, r + 1); P1UPD(f2, r + 2); P1UPD(f3, r + 3);
            P1UPD(f4, r + 4); P1UPD(f5, r + 5); P1UPD(f6, r + 6); P1UPD(f7, r + 7);
        }
        for (; r < rend; ++r) {
            f32x2 f0 = P1LOAD(r);
            P1UPD(f0, r);
        }
#undef P1LOAD
#undef P1UPD

        u64* base = part + (size_t)blk * 1536;   // [3][512]
        base[0 * 512 + c0] = a0; base[0 * 512 + c0 + 1] = b0;
        base[1 * 512 + c0] = a1; base[1 * 512 + c0 + 1] = b1;
        base[2 * 512 + c0] = a2; base[2 * 512 + c0 + 1] = b2;

    } else {
        // ---- topk1: top-4 smallest along rows of (8192, 4096), wave/row ----
        // 8 float4 in flight; sort-4 per float4 then one state merge.
        const int row = (bid - 1536) * 4 + wave;
        const f32x4* xr = (const f32x4*)(x1 + (size_t)row * 4096);
        u64 s0 = ~0ull, s1 = ~0ull, s2 = ~0ull, s3 = ~0ull;

#define K1UPD(f, b) { u64 c0_, c1_, c2_, c3_;                      \
        sort4_sm((f), (u32)(b), c0_, c1_, c2_, c3_);               \
        merge4_sm(s0, s1, s2, s3, c0_, c1_, c2_, c3_); }

        // 1024 float4/row; 16/lane = 2*8
        int v = lane;
        for (int it = 0; it < 2; ++it, v += 512) {
            f32x4 t0 = NTL4(&xr[v]);
            f32x4 t1 = NTL4(&xr[v + 64]);
            f32x4 t2 = NTL4(&xr[v + 128]);
            f32x4 t3 = NTL4(&xr[v + 192]);
            f32x4 t4 = NTL4(&xr[v + 256]);
            f32x4 t5 = NTL4(&xr[v + 320]);
            f32x4 t6 = NTL4(&xr[v + 384]);
            f32x4 t7 = NTL4(&xr[v + 448]);
            K1UPD(t0, v * 4);
            K1UPD(t1, (v + 64) * 4);
            K1UPD(t2, (v + 128) * 4);
            K1UPD(t3, (v + 192) * 4);
            K1UPD(t4, (v + 256) * 4);
            K1UPD(t5, (v + 320) * 4);
            K1UPD(t6, (v + 384) * 4);
            K1UPD(t7, (v + 448) * 4);
        }
#undef K1UPD

        for (int m = 1; m < 64; m <<= 1) {
            u64 b0 = shx64(s0, m), b1 = shx64(s1, m);
            u64 b2 = shx64(s2, m), b3 = shx64(s3, m);
            merge4_sm(s0, s1, s2, s3, b0, b1, b2, b3);
        }
        if (lane == 0) {
            o1v[row * 4 + 0] = val_of(s0);  o1v[row * 4 + 1] = val_of(s1);
            o1v[row * 4 + 2] = val_of(s2);  o1v[row * 4 + 3] = val_of(s3);
            o1i[row * 4 + 0] = idxf_sm(s0); o1i[row * 4 + 1] = idxf_sm(s1);
            o1i[row * 4 + 2] = idxf_sm(s2); o1i[row * 4 + 3] = idxf_sm(s3);
        }
    }
}

// Single-launch reduction: merge 512 partials per column + decode.
// Wave <-> column (128 blocks x 4 waves): lane l merges partials l+64j,
// then 6-step butterfly. ~6.3 MB read (L2-resident thanks to nt input loads).
__global__ __launch_bounds__(256) void topk2_reduce(
    const u64* __restrict__ part, float* __restrict__ outv, float* __restrict__ outi)
{
    const int wave = threadIdx.x >> 6;
    const int lane = threadIdx.x & 63;
    const int col  = blockIdx.x * 4 + wave;

    u64 a0 = 0, a1 = 0, a2 = 0;
#pragma unroll
    for (int j = 0; j < 8; ++j) {
        const u64* q = part + (size_t)(lane + 64 * j) * 1536 + col;
        merge3_lg(a0, a1, a2, q[0], q[512], q[1024]);
    }
    for (int m = 1; m < 64; m <<= 1) {
        u64 b0 = shx64(a0, m), b1 = shx64(a1, m), b2 = shx64(a2, m);
        merge3_lg(a0, a1, a2, b0, b1, b2);
    }

    if (lane == 0) {
        outv[0 * 512 + col] = val_of(a0);
        outv[1 * 512 + col] = val_of(a1);
        outv[2 * 512 + col] = val_of(a2);
        outi[0 * 512 + col] = idxf_lg(a0);
        outi[1 * 512 + col] = idxf_lg(a1);
        outi[2 * 512 + col] = idxf_lg(a2);
    }
}

// Fallback if workspace is too small (never expected): thread <-> column,
// coalesced row-major streaming, branchless.
__global__ __launch_bounds__(256) void topk2_direct(
    const float* __restrict__ x, float* __restrict__ outv, float* __restrict__ outi)
{
    const int col = blockIdx.x * 256 + threadIdx.x;
    u64 a0 = 0, a1 = 0, a2 = 0;
    for (int r = 0; r < 100000; ++r) {
        float v = x[(size_t)r * 512 + col];
        ins3_lg(a0, a1, a2, keylg(v, (u32)r));
    }
    outv[0 * 512 + col] = val_of(a0);
    outv[1 * 512 + col] = val_of(a1);
    outv[2 * 512 + col] = val_of(a2);
    outi[0 * 512 + col] = idxf_lg(a0);
    outi[1 * 512 + col] = idxf_lg(a1);
    outi[2 * 512 + col] = idxf_lg(a2);
}

extern "C" void kernel_launch(void* const* d_in, const int* in_sizes, int n_in,
                              void* d_out, int out_size, void* d_ws, size_t ws_size,
                              hipStream_t stream) {
    const float* v0 = (const float*)d_in[0];   // (4096, 32000)
    const float* v1 = (const float*)d_in[1];   // (8, 16, 64, 4096)
    const float* v2 = (const float*)d_in[2];   // (100000, 512)
    float* out = (float*)d_out;

    float* o_v4  = out;                 // (4096, 2) values
    float* o_v5  = out + 8192;          // (4096, 2) indices
    float* o_v7  = out + 16384;         // (8,16,64,4) values
    float* o_v8  = out + 49152;         // (8,16,64,4) indices
    float* o_v10 = out + 81920;         // (3, 512) values
    float* o_v11 = out + 83456;         // (3, 512) indices

    const int NB = 512;                           // phase-1 blocks / partials
    int rpb = (100000 + NB - 1) / NB;             // 196
    size_t need = (size_t)NB * 3 * 512 * sizeof(u64);   // ~6.3 MB

    if (ws_size >= need) {
        u64* part = (u64*)d_ws;                    // [512][3][512]
        mega_kernel<<<3584, 256, 0, stream>>>(v0, o_v4, o_v5,
                                              v1, o_v7, o_v8,
                                              v2, part, rpb, 1);
        topk2_reduce<<<128, 256, 0, stream>>>(part, o_v10, o_v11);
    } else {
        mega_kernel<<<3584, 256, 0, stream>>>(v0, o_v4, o_v5,
                                              v1, o_v7, o_v8,
                                              v2, (u64*)d_ws, rpb, 0);
        topk2_direct<<<2, 256, 0, stream>>>(v2, o_v10, o_v11);
    }
}